// Round 1
// baseline (1220.688 us; speedup 1.0000x reference)
//
#include <hip/hip_runtime.h>

#define DIMW 1024
#define NB 2
#define NSEQ 4096
#define MLAT 512
#define NH 16
#define HDIM 64
#define SKV 4608   // NSEQ + MLAT
#define LNEPS 1e-5f

// ---------------------------------------------------------------------------
// LayerNorm: one block per row of 1024 floats. 256 threads, float4 per thread.
// ---------------------------------------------------------------------------
__global__ __launch_bounds__(256) void ln_kernel(const float* __restrict__ in,
                                                 const float* __restrict__ g,
                                                 const float* __restrict__ bb,
                                                 float* __restrict__ out) {
  const int row = blockIdx.x;
  const int tid = threadIdx.x;
  const float4 x = reinterpret_cast<const float4*>(in + (size_t)row * DIMW)[tid];
  float s  = x.x + x.y + x.z + x.w;
  float ss = x.x * x.x + x.y * x.y + x.z * x.z + x.w * x.w;
#pragma unroll
  for (int off = 1; off < 64; off <<= 1) {
    s  += __shfl_xor(s, off);
    ss += __shfl_xor(ss, off);
  }
  __shared__ float red[8];
  const int wid = tid >> 6;
  if ((tid & 63) == 0) { red[wid] = s; red[4 + wid] = ss; }
  __syncthreads();
  const float S  = red[0] + red[1] + red[2] + red[3];
  const float SS = red[4] + red[5] + red[6] + red[7];
  const float mu  = S * (1.0f / DIMW);
  const float var = SS * (1.0f / DIMW) - mu * mu;
  const float rv  = rsqrtf(var + LNEPS);
  const float4 g4 = reinterpret_cast<const float4*>(g)[tid];
  const float4 b4 = reinterpret_cast<const float4*>(bb)[tid];
  float4 o;
  o.x = (x.x - mu) * rv * g4.x + b4.x;
  o.y = (x.y - mu) * rv * g4.y + b4.y;
  o.z = (x.z - mu) * rv * g4.z + b4.z;
  o.w = (x.w - mu) * rv * g4.w + b4.w;
  reinterpret_cast<float4*>(out + (size_t)row * DIMW)[tid] = o;
}

// ---------------------------------------------------------------------------
// fp32 GEMM, 128x128 tile, BK=16, 256 threads, 8x8 micro-tile (4+4 split).
// MODE 0: plain row-major out (final @ Wout)
// MODE 1: q epilogue  -> q_ws[b][h][m][hd] * HD^-0.5
// MODE 2: kv_x        -> k_ws/v_ws[b][h][n][hd], RoPE on hd<32 of k
// MODE 3: kv_latents  -> k_ws/v_ws[b][h][4096+m][hd], no RoPE
// ---------------------------------------------------------------------------
template <int MODE>
__global__ __launch_bounds__(256) void gemm_kernel(
    const float* __restrict__ A, const float* __restrict__ W, int ldw,
    float* __restrict__ oa, float* __restrict__ ob,
    const float* __restrict__ cosT, const float* __restrict__ sinT) {
  __shared__ float As[16][132];   // [k][m], +4 pad
  __shared__ float Bs[16][132];   // [k][n], +4 pad
  const int tid = threadIdx.x;
  const int tr = tid >> 4;        // 0..15
  const int tc = tid & 15;        // 0..15
  const int arow0 = blockIdx.x * 128;
  const int bcol0 = blockIdx.y * 128;

  const int a_r = tid >> 2;            // 0..63
  const int a_k = (tid & 3) << 2;      // 0,4,8,12
  const int w_k = tid >> 5;            // 0..7
  const int w_c = (tid & 31) << 2;     // 0..124

  float acc[8][8];
#pragma unroll
  for (int i = 0; i < 8; ++i)
#pragma unroll
    for (int j = 0; j < 8; ++j) acc[i][j] = 0.0f;

  const float* Ap0 = A + (size_t)(arow0 + a_r) * DIMW + a_k;
  const float* Ap1 = A + (size_t)(arow0 + a_r + 64) * DIMW + a_k;
  const float* Wp0 = W + (size_t)w_k * ldw + bcol0 + w_c;
  const float* Wp1 = W + (size_t)(w_k + 8) * ldw + bcol0 + w_c;

  float4 pa0 = *(const float4*)Ap0;
  float4 pa1 = *(const float4*)Ap1;
  float4 pw0 = *(const float4*)Wp0;
  float4 pw1 = *(const float4*)Wp1;

  for (int kt = 0; kt < DIMW / 16; ++kt) {
    __syncthreads();   // previous tile's compute done
    As[a_k + 0][a_r] = pa0.x;  As[a_k + 1][a_r] = pa0.y;
    As[a_k + 2][a_r] = pa0.z;  As[a_k + 3][a_r] = pa0.w;
    As[a_k + 0][a_r + 64] = pa1.x;  As[a_k + 1][a_r + 64] = pa1.y;
    As[a_k + 2][a_r + 64] = pa1.z;  As[a_k + 3][a_r + 64] = pa1.w;
    *(float4*)&Bs[w_k][w_c]     = pw0;
    *(float4*)&Bs[w_k + 8][w_c] = pw1;
    __syncthreads();
    if (kt < DIMW / 16 - 1) {  // prefetch next K-tile into regs
      const size_t ko = (size_t)(kt + 1) * 16;
      pa0 = *(const float4*)(Ap0 + ko);
      pa1 = *(const float4*)(Ap1 + ko);
      pw0 = *(const float4*)(Wp0 + ko * ldw);
      pw1 = *(const float4*)(Wp1 + ko * ldw);
    }
#pragma unroll
    for (int kk = 0; kk < 16; ++kk) {
      const float4 a0 = *(const float4*)&As[kk][tr << 2];
      const float4 a1 = *(const float4*)&As[kk][64 + (tr << 2)];
      const float4 b0 = *(const float4*)&Bs[kk][tc << 2];
      const float4 b1 = *(const float4*)&Bs[kk][64 + (tc << 2)];
      const float av[8] = {a0.x, a0.y, a0.z, a0.w, a1.x, a1.y, a1.z, a1.w};
      const float bv[8] = {b0.x, b0.y, b0.z, b0.w, b1.x, b1.y, b1.z, b1.w};
#pragma unroll
      for (int i = 0; i < 8; ++i)
#pragma unroll
        for (int j = 0; j < 8; ++j)
          acc[i][j] = fmaf(av[i], bv[j], acc[i][j]);
    }
  }

  // ---------------- epilogue ----------------
#pragma unroll
  for (int hi = 0; hi < 2; ++hi) {
#pragma unroll
    for (int i = 0; i < 4; ++i) {
      const int r = arow0 + hi * 64 + (tr << 2) + i;
      if (MODE == 0) {
#pragma unroll
        for (int hj = 0; hj < 2; ++hj)
#pragma unroll
          for (int j = 0; j < 4; ++j) {
            const int c = bcol0 + hj * 64 + (tc << 2) + j;
            oa[(size_t)r * DIMW + c] = acc[hi * 4 + i][hj * 4 + j];
          }
      } else if (MODE == 1) {
        const int b = r >> 9, m = r & 511;
#pragma unroll
        for (int hj = 0; hj < 2; ++hj)
#pragma unroll
          for (int j = 0; j < 4; ++j) {
            const int c = bcol0 + hj * 64 + (tc << 2) + j;
            const int h = c >> 6, hd = c & 63;
            oa[(size_t)((b * NH + h) * MLAT + m) * HDIM + hd] =
                acc[hi * 4 + i][hj * 4 + j] * 0.125f;  // HD^-0.5
          }
      } else {  // MODE 2 / 3 : KV scatter (+RoPE for MODE 2)
        int b, pos;
        if (MODE == 2) { b = r >> 12; pos = r & 4095; }
        else           { b = r >> 9;  pos = NSEQ + (r & 511); }
#pragma unroll
        for (int hj = 0; hj < 2; ++hj)
#pragma unroll
          for (int j = 0; j < 4; j += 2) {
            const int c = bcol0 + hj * 64 + (tc << 2) + j;
            const float v0 = acc[hi * 4 + i][hj * 4 + j];
            const float v1 = acc[hi * 4 + i][hj * 4 + j + 1];
            if (c < 1024) {           // K half
              const int h = c >> 6, hd = c & 63;
              float* dst = oa + (size_t)((b * NH + h) * SKV + pos) * HDIM + hd;
              if (MODE == 2 && hd < 32) {
                const float cs = cosT[pos * 16 + (hd >> 1)];
                const float sn = sinT[pos * 16 + (hd >> 1)];
                dst[0] = v0 * cs - v1 * sn;
                dst[1] = v1 * cs + v0 * sn;
              } else {
                dst[0] = v0; dst[1] = v1;
              }
            } else {                  // V half
              const int c2 = c - 1024;
              const int h = c2 >> 6, hd = c2 & 63;
              float* dst = ob + (size_t)((b * NH + h) * SKV + pos) * HDIM + hd;
              dst[0] = v0; dst[1] = v1;
            }
          }
      }
    }
  }
}

// ---------------------------------------------------------------------------
// Flash attention fp32: block = (q-tile of 64) x (b,h). KT=64 key tiles,
// online softmax (m,l,c in LDS), 256 threads.
// score map: thread (tq=tid>>4, tk=tid&15) -> rows {tq+16i}, cols {tk+16j}
// PV map:    thread (rq=tid>>4, td=tid&15) -> rows {rq+16i}, dims {td*4..+3}
// ---------------------------------------------------------------------------
__global__ __launch_bounds__(256) void attn_kernel(const float* __restrict__ q,
                                                   const float* __restrict__ k,
                                                   const float* __restrict__ v,
                                                   float* __restrict__ ao) {
  __shared__ float Qs[64][68];
  __shared__ float Ks[64][68];
  __shared__ float Vs[64][68];
  __shared__ float Ps[64][68];
  __shared__ float m_s[64], l_s[64], c_s[64];

  const int tid = threadIdx.x;
  const int qt  = blockIdx.x;   // 0..7
  const int bh  = blockIdx.y;   // 0..31
  const size_t kvbase = (size_t)bh * SKV * HDIM;
  const float* qp = q + (size_t)bh * MLAT * HDIM + (size_t)qt * 64 * HDIM;

#pragma unroll
  for (int i = 0; i < 4; ++i) {   // load Q tile (already scaled)
    const int idx = tid + 256 * i;
    const int r = idx >> 4, c4 = (idx & 15) << 2;
    *(float4*)&Qs[r][c4] = *(const float4*)&qp[r * HDIM + c4];
  }
  if (tid < 64) { m_s[tid] = -1e30f; l_s[tid] = 0.0f; }

  float O[4][4];
#pragma unroll
  for (int i = 0; i < 4; ++i)
#pragma unroll
    for (int d = 0; d < 4; ++d) O[i][d] = 0.0f;

  const int tq = tid >> 4, tk = tid & 15;
  const int rq = tq, td = tk;

  for (int kt = 0; kt < SKV / 64; ++kt) {
    __syncthreads();   // previous PV done, Q ready on first iter
    const float* kp = k + kvbase + (size_t)kt * 64 * HDIM;
    const float* vp = v + kvbase + (size_t)kt * 64 * HDIM;
#pragma unroll
    for (int i = 0; i < 4; ++i) {
      const int idx = tid + 256 * i;
      const int r = idx >> 4, c4 = (idx & 15) << 2;
      *(float4*)&Ks[r][c4] = *(const float4*)&kp[r * HDIM + c4];
      *(float4*)&Vs[r][c4] = *(const float4*)&vp[r * HDIM + c4];
    }
    __syncthreads();

    // ---- scores: 4q x 4k per thread, dot length 64 ----
    float sc[4][4];
#pragma unroll
    for (int i = 0; i < 4; ++i)
#pragma unroll
      for (int j = 0; j < 4; ++j) sc[i][j] = 0.0f;
#pragma unroll
    for (int kk = 0; kk < 16; ++kk) {
      float4 qv[4], kv[4];
#pragma unroll
      for (int i = 0; i < 4; ++i) qv[i] = *(const float4*)&Qs[tq + 16 * i][kk << 2];
#pragma unroll
      for (int j = 0; j < 4; ++j) kv[j] = *(const float4*)&Ks[tk + 16 * j][kk << 2];
#pragma unroll
      for (int i = 0; i < 4; ++i)
#pragma unroll
        for (int j = 0; j < 4; ++j) {
          sc[i][j] = fmaf(qv[i].x, kv[j].x, sc[i][j]);
          sc[i][j] = fmaf(qv[i].y, kv[j].y, sc[i][j]);
          sc[i][j] = fmaf(qv[i].z, kv[j].z, sc[i][j]);
          sc[i][j] = fmaf(qv[i].w, kv[j].w, sc[i][j]);
        }
    }
#pragma unroll
    for (int i = 0; i < 4; ++i)
#pragma unroll
      for (int j = 0; j < 4; ++j) Ps[tq + 16 * i][tk + 16 * j] = sc[i][j];
    __syncthreads();

    // ---- online softmax: 4 lanes per row, 16 values each ----
    {
      const int r = tid >> 2, qq = tid & 3;
      float4 pv[4];
#pragma unroll
      for (int u = 0; u < 4; ++u) pv[u] = *(const float4*)&Ps[r][(qq << 4) + (u << 2)];
      float tmax = -1e30f;
#pragma unroll
      for (int u = 0; u < 4; ++u) {
        tmax = fmaxf(tmax, fmaxf(fmaxf(pv[u].x, pv[u].y), fmaxf(pv[u].z, pv[u].w)));
      }
      tmax = fmaxf(tmax, __shfl_xor(tmax, 1));
      tmax = fmaxf(tmax, __shfl_xor(tmax, 2));
      const float mold = m_s[r];
      const float mnew = fmaxf(mold, tmax);
      float tsum = 0.0f;
#pragma unroll
      for (int u = 0; u < 4; ++u) {
        pv[u].x = __expf(pv[u].x - mnew);
        pv[u].y = __expf(pv[u].y - mnew);
        pv[u].z = __expf(pv[u].z - mnew);
        pv[u].w = __expf(pv[u].w - mnew);
        tsum += pv[u].x + pv[u].y + pv[u].z + pv[u].w;
      }
      tsum += __shfl_xor(tsum, 1);
      tsum += __shfl_xor(tsum, 2);
      const float crow = __expf(mold - mnew);
      if (qq == 0) {
        m_s[r] = mnew;
        l_s[r] = l_s[r] * crow + tsum;
        c_s[r] = crow;
      }
#pragma unroll
      for (int u = 0; u < 4; ++u) *(float4*)&Ps[r][(qq << 4) + (u << 2)] = pv[u];
    }
    __syncthreads();

    // ---- PV: rescale + accumulate ----
    float cr[4];
#pragma unroll
    for (int i = 0; i < 4; ++i) cr[i] = c_s[rq + 16 * i];
#pragma unroll
    for (int i = 0; i < 4; ++i)
#pragma unroll
      for (int d = 0; d < 4; ++d) O[i][d] *= cr[i];
#pragma unroll
    for (int j4 = 0; j4 < 16; ++j4) {
      float4 p4[4], vv[4];
#pragma unroll
      for (int i = 0; i < 4; ++i) p4[i] = *(const float4*)&Ps[rq + 16 * i][j4 << 2];
#pragma unroll
      for (int jj = 0; jj < 4; ++jj) vv[jj] = *(const float4*)&Vs[(j4 << 2) + jj][td << 2];
#pragma unroll
      for (int i = 0; i < 4; ++i) {
        const float pw[4] = {p4[i].x, p4[i].y, p4[i].z, p4[i].w};
#pragma unroll
        for (int jj = 0; jj < 4; ++jj) {
          O[i][0] = fmaf(pw[jj], vv[jj].x, O[i][0]);
          O[i][1] = fmaf(pw[jj], vv[jj].y, O[i][1]);
          O[i][2] = fmaf(pw[jj], vv[jj].z, O[i][2]);
          O[i][3] = fmaf(pw[jj], vv[jj].w, O[i][3]);
        }
      }
    }
  }

  // ---- epilogue: divide by l, write ao[b][m][h*64+hd] ----
  const int b = bh >> 4, h = bh & 15;
#pragma unroll
  for (int i = 0; i < 4; ++i) {
    const float linv = 1.0f / l_s[rq + 16 * i];
    const int qglob = qt * 64 + rq + 16 * i;
    float4 o4;
    o4.x = O[i][0] * linv; o4.y = O[i][1] * linv;
    o4.z = O[i][2] * linv; o4.w = O[i][3] * linv;
    *(float4*)&ao[(size_t)(b * MLAT + qglob) * DIMW + h * HDIM + (td << 2)] = o4;
  }
}

// ---------------------------------------------------------------------------
extern "C" void kernel_launch(void* const* d_in, const int* in_sizes, int n_in,
                              void* d_out, int out_size, void* d_ws, size_t ws_size,
                              hipStream_t stream) {
  const float* x    = (const float*)d_in[0];
  const float* lat  = (const float*)d_in[1];
  const float* cosT = (const float*)d_in[2];
  const float* sinT = (const float*)d_in[3];
  const float* Wq   = (const float*)d_in[4];
  const float* Wkv  = (const float*)d_in[5];
  const float* Wout = (const float*)d_in[6];
  const float* gx   = (const float*)d_in[7];
  const float* bx   = (const float*)d_in[8];
  const float* gl   = (const float*)d_in[9];
  const float* bl   = (const float*)d_in[10];
  float* out = (float*)d_out;

  float* ws = (float*)d_ws;
  float* xn = ws;                                   // 2*4096*1024
  float* ln = xn + (size_t)NB * NSEQ * DIMW;        // 2*512*1024
  float* qw = ln + (size_t)NB * MLAT * DIMW;        // 2*16*512*64
  float* kw = qw + (size_t)NB * MLAT * DIMW;        // 2*16*4608*64
  float* vw = kw + (size_t)NB * NH * SKV * HDIM;    // 2*16*4608*64
  float* ao = vw + (size_t)NB * NH * SKV * HDIM;    // 2*512*1024
  // total: ~121.6 MB of d_ws

  ln_kernel<<<dim3(NB * NSEQ), dim3(256), 0, stream>>>(x, gx, bx, xn);
  ln_kernel<<<dim3(NB * MLAT), dim3(256), 0, stream>>>(lat, gl, bl, ln);

  // q = ln @ Wq  (1024 x 1024 x 1024), scaled
  gemm_kernel<1><<<dim3(8, 8), dim3(256), 0, stream>>>(
      ln, Wq, DIMW, qw, nullptr, nullptr, nullptr);
  // kv_x = xn @ Wkv (8192 x 1024 x 2048), RoPE on k
  gemm_kernel<2><<<dim3(64, 16), dim3(256), 0, stream>>>(
      xn, Wkv, 2 * DIMW, kw, vw, cosT, sinT);
  // kv_l = ln @ Wkv (1024 x 1024 x 2048)
  gemm_kernel<3><<<dim3(8, 16), dim3(256), 0, stream>>>(
      ln, Wkv, 2 * DIMW, kw, vw, nullptr, nullptr);

  // attention -> ao[b][m][h*hd]
  attn_kernel<<<dim3(8, 32), dim3(256), 0, stream>>>(qw, kw, vw, ao);

  // out = ao @ Wout (1024 x 1024 x 1024)
  gemm_kernel<0><<<dim3(8, 8), dim3(256), 0, stream>>>(
      ao, Wout, DIMW, out, nullptr, nullptr, nullptr);
}

// Round 2
// 859.889 us; speedup vs baseline: 1.4196x; 1.4196x over previous
//
#include <hip/hip_runtime.h>
#include <hip/hip_bf16.h>

#define DIMW 1024
#define NB 2
#define NSEQ 4096
#define MLAT 512
#define NH 16
#define HDIM 64
#define SKV 4608   // NSEQ + MLAT
#define LNEPS 1e-5f

typedef __attribute__((ext_vector_type(8))) short bf16x8;
typedef __attribute__((ext_vector_type(4))) float f32x4;

static __device__ __forceinline__ ushort f2bf(float f) {
  __hip_bfloat16 h = __float2bfloat16(f);
  return *reinterpret_cast<ushort*>(&h);
}

// ---------------------------------------------------------------------------
// LayerNorm: one block per row of 1024 floats -> bf16 out. 256 thr, float4.
// ---------------------------------------------------------------------------
__global__ __launch_bounds__(256) void ln_kernel(const float* __restrict__ in,
                                                 const float* __restrict__ g,
                                                 const float* __restrict__ bb,
                                                 ushort* __restrict__ out) {
  const int row = blockIdx.x;
  const int tid = threadIdx.x;
  const float4 x = reinterpret_cast<const float4*>(in + (size_t)row * DIMW)[tid];
  float s  = x.x + x.y + x.z + x.w;
  float ss = x.x * x.x + x.y * x.y + x.z * x.z + x.w * x.w;
#pragma unroll
  for (int off = 1; off < 64; off <<= 1) {
    s  += __shfl_xor(s, off);
    ss += __shfl_xor(ss, off);
  }
  __shared__ float red[8];
  const int wid = tid >> 6;
  if ((tid & 63) == 0) { red[wid] = s; red[4 + wid] = ss; }
  __syncthreads();
  const float S  = red[0] + red[1] + red[2] + red[3];
  const float SS = red[4] + red[5] + red[6] + red[7];
  const float mu  = S * (1.0f / DIMW);
  const float var = SS * (1.0f / DIMW) - mu * mu;
  const float rv  = rsqrtf(var + LNEPS);
  const float4 g4 = reinterpret_cast<const float4*>(g)[tid];
  const float4 b4 = reinterpret_cast<const float4*>(bb)[tid];
  ushort4 o = make_ushort4(f2bf((x.x - mu) * rv * g4.x + b4.x),
                           f2bf((x.y - mu) * rv * g4.y + b4.y),
                           f2bf((x.z - mu) * rv * g4.z + b4.z),
                           f2bf((x.w - mu) * rv * g4.w + b4.w));
  *reinterpret_cast<ushort4*>(out + (size_t)row * DIMW + tid * 4) = o;
}

// ---------------------------------------------------------------------------
// Transpose + cast: W [K][Nn] f32 -> WT [Nn][K] bf16. 64x64 tiles.
// ---------------------------------------------------------------------------
__global__ __launch_bounds__(256) void tcast_kernel(const float* __restrict__ W,
                                                    ushort* __restrict__ WT,
                                                    int K, int Nn) {
  __shared__ __align__(16) ushort T[64][72];
  const int t = threadIdx.x;
  const int n0 = blockIdx.x * 64, k0 = blockIdx.y * 64;
#pragma unroll
  for (int i = 0; i < 4; ++i) {
    const int kk = (t >> 4) + 16 * i;
    const int nn = (t & 15) * 4;
    const float4 w = *(const float4*)&W[(size_t)(k0 + kk) * Nn + n0 + nn];
    T[nn + 0][kk] = f2bf(w.x);
    T[nn + 1][kk] = f2bf(w.y);
    T[nn + 2][kk] = f2bf(w.z);
    T[nn + 3][kk] = f2bf(w.w);
  }
  __syncthreads();
#pragma unroll
  for (int i = 0; i < 4; ++i) {
    const int nn = (t >> 4) + 16 * i;
    const int kk = (t & 15) * 4;
    *(ushort4*)&WT[(size_t)(n0 + nn) * K + k0 + kk] = *(ushort4*)&T[nn][kk];
  }
}

// ---------------------------------------------------------------------------
// f32 -> bf16 elementwise cast (4 elems/thread)
// ---------------------------------------------------------------------------
__global__ __launch_bounds__(256) void castbf_kernel(const float* __restrict__ in,
                                                     ushort* __restrict__ out) {
  const int i = blockIdx.x * 256 + threadIdx.x;
  const float4 v = reinterpret_cast<const float4*>(in)[i];
  reinterpret_cast<ushort4*>(out)[i] =
      make_ushort4(f2bf(v.x), f2bf(v.y), f2bf(v.z), f2bf(v.w));
}

// ---------------------------------------------------------------------------
// bf16 MFMA GEMM: C[M][N] = A[M][1024] @ W, W given pre-transposed as
// B[N][1024] bf16 (row n = column n of W). 128x128 tile, BK=64, 4 waves,
// each wave 64x64 via 4x4 fragments of v_mfma_f32_16x16x32_bf16.
// MODE 0: o0[row*1024+col] = v                      (final @ Wout -> d_out)
// MODE 1: fused ln GEMM, N=3072: col<1024 -> q (x0.125, scatter),
//         col<2048 -> k_l scatter (pos=4096+m), else v_l scatter
// MODE 2: kv_x, N=2048: col<1024 -> k_x scatter + RoPE(hd<32), else v_x
// ---------------------------------------------------------------------------
template <int MODE>
__global__ __launch_bounds__(256, 2) void gemm_bf16(
    const ushort* __restrict__ A, const ushort* __restrict__ B0,
    const ushort* __restrict__ B1,
    float* __restrict__ o0, float* __restrict__ o1, float* __restrict__ o2,
    const float* __restrict__ cosT, const float* __restrict__ sinT) {
  __shared__ __align__(16) ushort sm[2 * 128 * 72];  // 36 KB, pitch 72 elems
  ushort* As = sm;
  ushort* Bs = sm + 128 * 72;

  const int t = threadIdx.x;
  const int lane = t & 63;
  const int wid = t >> 6;
  const int wr = wid >> 1, wc = wid & 1;
  const int arow0 = blockIdx.x * 128;
  const int bcol0 = blockIdx.y * 128;

  const ushort* Bg;
  if (MODE == 1)
    Bg = (bcol0 < 1024) ? (B0 + (size_t)bcol0 * DIMW)
                        : (B1 + (size_t)(bcol0 - 1024) * DIMW);
  else
    Bg = B0 + (size_t)bcol0 * DIMW;
  const ushort* Ag = A + (size_t)arow0 * DIMW;

  const int srow = t >> 3;        // 0..31 (staging row within group of 32)
  const int skk  = (t & 7) * 8;   // 0..56 (staging k offset)

  f32x4 acc[4][4];
#pragma unroll
  for (int fm = 0; fm < 4; ++fm)
#pragma unroll
    for (int fn = 0; fn < 4; ++fn) acc[fm][fn] = (f32x4)(0.0f);

  int4 ra[4], rb[4];
#pragma unroll
  for (int i = 0; i < 4; ++i) {
    const int row = i * 32 + srow;
    ra[i] = *(const int4*)(Ag + (size_t)row * DIMW + skk);
    rb[i] = *(const int4*)(Bg + (size_t)row * DIMW + skk);
  }

  const int aoff = (wr * 64 + (lane & 15)) * 72 + (lane >> 4) * 8;
  const int boff = 128 * 72 + (wc * 64 + (lane & 15)) * 72 + (lane >> 4) * 8;

  for (int kt = 0; kt < 16; ++kt) {
    __syncthreads();
#pragma unroll
    for (int i = 0; i < 4; ++i) {
      *(int4*)(As + (i * 32 + srow) * 72 + skk) = ra[i];
      *(int4*)(Bs + (i * 32 + srow) * 72 + skk) = rb[i];
    }
    __syncthreads();
    if (kt < 15) {
      const size_t ko = (size_t)(kt + 1) * 64 + skk;
#pragma unroll
      for (int i = 0; i < 4; ++i) {
        const int row = i * 32 + srow;
        ra[i] = *(const int4*)(Ag + (size_t)row * DIMW + ko);
        rb[i] = *(const int4*)(Bg + (size_t)row * DIMW + ko);
      }
    }
#pragma unroll
    for (int s = 0; s < 2; ++s) {
      bf16x8 af[4], bfr[4];
#pragma unroll
      for (int f = 0; f < 4; ++f) {
        af[f]  = *(const bf16x8*)(sm + aoff + f * 16 * 72 + s * 32);
        bfr[f] = *(const bf16x8*)(sm + boff + f * 16 * 72 + s * 32);
      }
#pragma unroll
      for (int fm = 0; fm < 4; ++fm)
#pragma unroll
        for (int fn = 0; fn < 4; ++fn)
          acc[fm][fn] = __builtin_amdgcn_mfma_f32_16x16x32_bf16(
              af[fm], bfr[fn], acc[fm][fn], 0, 0, 0);
    }
  }

  // ---------------- epilogue ----------------
  const int lr0 = (lane >> 4) * 4;
  const int lc  = lane & 15;
#pragma unroll
  for (int fm = 0; fm < 4; ++fm) {
#pragma unroll
    for (int fn = 0; fn < 4; ++fn) {
#pragma unroll
      for (int r = 0; r < 4; ++r) {
        const int row = arow0 + wr * 64 + fm * 16 + lr0 + r;
        const int col = bcol0 + wc * 64 + fn * 16 + lc;
        const float v = acc[fm][fn][r];
        if (MODE == 0) {
          o0[(size_t)row * DIMW + col] = v;
        } else if (MODE == 1) {
          const int b = row >> 9, m = row & 511;
          if (col < 1024) {
            o0[(size_t)((b * NH + (col >> 6)) * MLAT + m) * HDIM + (col & 63)] =
                v * 0.125f;
          } else if (col < 2048) {
            const int c2 = col - 1024;
            o1[(size_t)((b * NH + (c2 >> 6)) * SKV + NSEQ + m) * HDIM + (c2 & 63)] = v;
          } else {
            const int c2 = col - 2048;
            o2[(size_t)((b * NH + (c2 >> 6)) * SKV + NSEQ + m) * HDIM + (c2 & 63)] = v;
          }
        } else {  // MODE 2
          const int b = row >> 12, pos = row & 4095;
          const float p = __shfl_xor(v, 1);  // partner column's value
          if (col < 1024) {
            const int hd = col & 63;
            float ov = v;
            if (hd < 32) {
              const float cs = cosT[pos * 16 + (hd >> 1)];
              const float sn = sinT[pos * 16 + (hd >> 1)];
              ov = (hd & 1) ? fmaf(v, cs, p * sn) : fmaf(v, cs, -p * sn);
            }
            o1[(size_t)((b * NH + (col >> 6)) * SKV + pos) * HDIM + hd] = ov;
          } else {
            const int c2 = col - 1024;
            o2[(size_t)((b * NH + (c2 >> 6)) * SKV + pos) * HDIM + (c2 & 63)] = v;
          }
        }
      }
    }
  }
}

// ---------------------------------------------------------------------------
// Flash attention fp32 (UNCHANGED from R1 baseline)
// ---------------------------------------------------------------------------
__global__ __launch_bounds__(256) void attn_kernel(const float* __restrict__ q,
                                                   const float* __restrict__ k,
                                                   const float* __restrict__ v,
                                                   float* __restrict__ ao) {
  __shared__ float Qs[64][68];
  __shared__ float Ks[64][68];
  __shared__ float Vs[64][68];
  __shared__ float Ps[64][68];
  __shared__ float m_s[64], l_s[64], c_s[64];

  const int tid = threadIdx.x;
  const int qt  = blockIdx.x;   // 0..7
  const int bh  = blockIdx.y;   // 0..31
  const size_t kvbase = (size_t)bh * SKV * HDIM;
  const float* qp = q + (size_t)bh * MLAT * HDIM + (size_t)qt * 64 * HDIM;

#pragma unroll
  for (int i = 0; i < 4; ++i) {
    const int idx = tid + 256 * i;
    const int r = idx >> 4, c4 = (idx & 15) << 2;
    *(float4*)&Qs[r][c4] = *(const float4*)&qp[r * HDIM + c4];
  }
  if (tid < 64) { m_s[tid] = -1e30f; l_s[tid] = 0.0f; }

  float O[4][4];
#pragma unroll
  for (int i = 0; i < 4; ++i)
#pragma unroll
    for (int d = 0; d < 4; ++d) O[i][d] = 0.0f;

  const int tq = tid >> 4, tk = tid & 15;
  const int rq = tq, td = tk;

  for (int kt = 0; kt < SKV / 64; ++kt) {
    __syncthreads();
    const float* kp = k + kvbase + (size_t)kt * 64 * HDIM;
    const float* vp = v + kvbase + (size_t)kt * 64 * HDIM;
#pragma unroll
    for (int i = 0; i < 4; ++i) {
      const int idx = tid + 256 * i;
      const int r = idx >> 4, c4 = (idx & 15) << 2;
      *(float4*)&Ks[r][c4] = *(const float4*)&kp[r * HDIM + c4];
      *(float4*)&Vs[r][c4] = *(const float4*)&vp[r * HDIM + c4];
    }
    __syncthreads();

    float sc[4][4];
#pragma unroll
    for (int i = 0; i < 4; ++i)
#pragma unroll
      for (int j = 0; j < 4; ++j) sc[i][j] = 0.0f;
#pragma unroll
    for (int kk = 0; kk < 16; ++kk) {
      float4 qv[4], kv[4];
#pragma unroll
      for (int i = 0; i < 4; ++i) qv[i] = *(const float4*)&Qs[tq + 16 * i][kk << 2];
#pragma unroll
      for (int j = 0; j < 4; ++j) kv[j] = *(const float4*)&Ks[tk + 16 * j][kk << 2];
#pragma unroll
      for (int i = 0; i < 4; ++i)
#pragma unroll
        for (int j = 0; j < 4; ++j) {
          sc[i][j] = fmaf(qv[i].x, kv[j].x, sc[i][j]);
          sc[i][j] = fmaf(qv[i].y, kv[j].y, sc[i][j]);
          sc[i][j] = fmaf(qv[i].z, kv[j].z, sc[i][j]);
          sc[i][j] = fmaf(qv[i].w, kv[j].w, sc[i][j]);
        }
    }
#pragma unroll
    for (int i = 0; i < 4; ++i)
#pragma unroll
      for (int j = 0; j < 4; ++j) Ps[tq + 16 * i][tk + 16 * j] = sc[i][j];
    __syncthreads();

    {
      const int r = tid >> 2, qq = tid & 3;
      float4 pv[4];
#pragma unroll
      for (int u = 0; u < 4; ++u) pv[u] = *(const float4*)&Ps[r][(qq << 4) + (u << 2)];
      float tmax = -1e30f;
#pragma unroll
      for (int u = 0; u < 4; ++u) {
        tmax = fmaxf(tmax, fmaxf(fmaxf(pv[u].x, pv[u].y), fmaxf(pv[u].z, pv[u].w)));
      }
      tmax = fmaxf(tmax, __shfl_xor(tmax, 1));
      tmax = fmaxf(tmax, __shfl_xor(tmax, 2));
      const float mold = m_s[r];
      const float mnew = fmaxf(mold, tmax);
      float tsum = 0.0f;
#pragma unroll
      for (int u = 0; u < 4; ++u) {
        pv[u].x = __expf(pv[u].x - mnew);
        pv[u].y = __expf(pv[u].y - mnew);
        pv[u].z = __expf(pv[u].z - mnew);
        pv[u].w = __expf(pv[u].w - mnew);
        tsum += pv[u].x + pv[u].y + pv[u].z + pv[u].w;
      }
      tsum += __shfl_xor(tsum, 1);
      tsum += __shfl_xor(tsum, 2);
      const float crow = __expf(mold - mnew);
      if (qq == 0) {
        m_s[r] = mnew;
        l_s[r] = l_s[r] * crow + tsum;
        c_s[r] = crow;
      }
#pragma unroll
      for (int u = 0; u < 4; ++u) *(float4*)&Ps[r][(qq << 4) + (u << 2)] = pv[u];
    }
    __syncthreads();

    float cr[4];
#pragma unroll
    for (int i = 0; i < 4; ++i) cr[i] = c_s[rq + 16 * i];
#pragma unroll
    for (int i = 0; i < 4; ++i)
#pragma unroll
      for (int d = 0; d < 4; ++d) O[i][d] *= cr[i];
#pragma unroll
    for (int j4 = 0; j4 < 16; ++j4) {
      float4 p4[4], vv[4];
#pragma unroll
      for (int i = 0; i < 4; ++i) p4[i] = *(const float4*)&Ps[rq + 16 * i][j4 << 2];
#pragma unroll
      for (int jj = 0; jj < 4; ++jj) vv[jj] = *(const float4*)&Vs[(j4 << 2) + jj][td << 2];
#pragma unroll
      for (int i = 0; i < 4; ++i) {
        const float pw[4] = {p4[i].x, p4[i].y, p4[i].z, p4[i].w};
#pragma unroll
        for (int jj = 0; jj < 4; ++jj) {
          O[i][0] = fmaf(pw[jj], vv[jj].x, O[i][0]);
          O[i][1] = fmaf(pw[jj], vv[jj].y, O[i][1]);
          O[i][2] = fmaf(pw[jj], vv[jj].z, O[i][2]);
          O[i][3] = fmaf(pw[jj], vv[jj].w, O[i][3]);
        }
      }
    }
  }

  const int b = bh >> 4, h = bh & 15;
#pragma unroll
  for (int i = 0; i < 4; ++i) {
    const float linv = 1.0f / l_s[rq + 16 * i];
    const int qglob = qt * 64 + rq + 16 * i;
    float4 o4;
    o4.x = O[i][0] * linv; o4.y = O[i][1] * linv;
    o4.z = O[i][2] * linv; o4.w = O[i][3] * linv;
    *(float4*)&ao[(size_t)(b * MLAT + qglob) * DIMW + h * HDIM + (td << 2)] = o4;
  }
}

// ---------------------------------------------------------------------------
extern "C" void kernel_launch(void* const* d_in, const int* in_sizes, int n_in,
                              void* d_out, int out_size, void* d_ws, size_t ws_size,
                              hipStream_t stream) {
  const float* x    = (const float*)d_in[0];
  const float* lat  = (const float*)d_in[1];
  const float* cosT = (const float*)d_in[2];
  const float* sinT = (const float*)d_in[3];
  const float* Wq   = (const float*)d_in[4];
  const float* Wkv  = (const float*)d_in[5];
  const float* Wout = (const float*)d_in[6];
  const float* gx   = (const float*)d_in[7];
  const float* bx   = (const float*)d_in[8];
  const float* gl   = (const float*)d_in[9];
  const float* bl   = (const float*)d_in[10];
  float* out = (float*)d_out;

  // ---- workspace layout (bf16 region first, then fp32) ----
  ushort* xnb   = (ushort*)d_ws;                       // 8192*1024
  ushort* lnb   = xnb   + (size_t)8192 * 1024;         // 1024*1024
  ushort* WqT   = lnb   + (size_t)1024 * 1024;         // 1024*1024
  ushort* WkvT  = WqT   + (size_t)1024 * 1024;         // 2048*1024
  ushort* WoutT = WkvT  + (size_t)2048 * 1024;         // 1024*1024
  ushort* aob   = WoutT + (size_t)1024 * 1024;         // 1024*1024
  float*  qw    = (float*)(aob + (size_t)1024 * 1024); // 2*16*512*64
  float*  kw    = qw + (size_t)NB * NH * MLAT * HDIM;  // 2*16*4608*64
  float*  vw    = kw + (size_t)NB * NH * SKV * HDIM;
  float*  ao    = vw + (size_t)NB * NH * SKV * HDIM;   // 1024*1024
  // total ~113 MB

  ln_kernel<<<dim3(NB * NSEQ), dim3(256), 0, stream>>>(x, gx, bx, xnb);
  ln_kernel<<<dim3(NB * MLAT), dim3(256), 0, stream>>>(lat, gl, bl, lnb);

  tcast_kernel<<<dim3(16, 16), dim3(256), 0, stream>>>(Wq,   WqT,   DIMW, 1024);
  tcast_kernel<<<dim3(32, 16), dim3(256), 0, stream>>>(Wkv,  WkvT,  DIMW, 2048);
  tcast_kernel<<<dim3(16, 16), dim3(256), 0, stream>>>(Wout, WoutT, DIMW, 1024);

  // fused: [q | k_l | v_l] = ln @ [Wq | Wkv]   (M=1024, N=3072)
  gemm_bf16<1><<<dim3(8, 24), dim3(256), 0, stream>>>(
      lnb, WqT, WkvT, qw, kw, vw, nullptr, nullptr);
  // kv_x = xn @ Wkv (M=8192, N=2048), RoPE on k
  gemm_bf16<2><<<dim3(64, 16), dim3(256), 0, stream>>>(
      xnb, WkvT, nullptr, nullptr, kw, vw, cosT, sinT);

  attn_kernel<<<dim3(8, 32), dim3(256), 0, stream>>>(qw, kw, vw, ao);

  castbf_kernel<<<dim3(1024), dim3(256), 0, stream>>>(ao, aob);

  // out = ao @ Wout (M=1024, N=1024)
  gemm_bf16<0><<<dim3(8, 8), dim3(256), 0, stream>>>(
      aob, WoutT, nullptr, out, nullptr, nullptr, nullptr, nullptr);
}

// Round 4
// 550.934 us; speedup vs baseline: 2.2157x; 1.5608x over previous
//
#include <hip/hip_runtime.h>
#include <hip/hip_bf16.h>

#define DIMW 1024
#define NB 2
#define NSEQ 4096
#define MLAT 512
#define NH 16
#define HDIM 64
#define SKV 4608   // NSEQ + MLAT
#define LNEPS 1e-5f

typedef __attribute__((ext_vector_type(8))) short bf16x8;
typedef __attribute__((ext_vector_type(4))) float f32x4;

static __device__ __forceinline__ ushort f2bf(float f) {
  __hip_bfloat16 h = __float2bfloat16(f);
  return *reinterpret_cast<ushort*>(&h);
}

// ---------------------------------------------------------------------------
// LayerNorm: one block per row of 1024 floats -> bf16 out.
// ---------------------------------------------------------------------------
__global__ __launch_bounds__(256) void ln_kernel(const float* __restrict__ in,
                                                 const float* __restrict__ g,
                                                 const float* __restrict__ bb,
                                                 ushort* __restrict__ out) {
  const int row = blockIdx.x;
  const int tid = threadIdx.x;
  const float4 x = reinterpret_cast<const float4*>(in + (size_t)row * DIMW)[tid];
  float s  = x.x + x.y + x.z + x.w;
  float ss = x.x * x.x + x.y * x.y + x.z * x.z + x.w * x.w;
#pragma unroll
  for (int off = 1; off < 64; off <<= 1) {
    s  += __shfl_xor(s, off);
    ss += __shfl_xor(ss, off);
  }
  __shared__ float red[8];
  const int wid = tid >> 6;
  if ((tid & 63) == 0) { red[wid] = s; red[4 + wid] = ss; }
  __syncthreads();
  const float S  = red[0] + red[1] + red[2] + red[3];
  const float SS = red[4] + red[5] + red[6] + red[7];
  const float mu  = S * (1.0f / DIMW);
  const float var = SS * (1.0f / DIMW) - mu * mu;
  const float rv  = rsqrtf(var + LNEPS);
  const float4 g4 = reinterpret_cast<const float4*>(g)[tid];
  const float4 b4 = reinterpret_cast<const float4*>(bb)[tid];
  ushort4 o = make_ushort4(f2bf((x.x - mu) * rv * g4.x + b4.x),
                           f2bf((x.y - mu) * rv * g4.y + b4.y),
                           f2bf((x.z - mu) * rv * g4.z + b4.z),
                           f2bf((x.w - mu) * rv * g4.w + b4.w));
  *reinterpret_cast<ushort4*>(out + (size_t)row * DIMW + tid * 4) = o;
}

// ---------------------------------------------------------------------------
// Transpose + cast: W [K][Nn] f32 -> WT [Nn][K] bf16. 64x64 tiles.
// ---------------------------------------------------------------------------
__global__ __launch_bounds__(256) void tcast_kernel(const float* __restrict__ W,
                                                    ushort* __restrict__ WT,
                                                    int K, int Nn) {
  __shared__ __align__(16) ushort T[64][72];
  const int t = threadIdx.x;
  const int n0 = blockIdx.x * 64, k0 = blockIdx.y * 64;
#pragma unroll
  for (int i = 0; i < 4; ++i) {
    const int kk = (t >> 4) + 16 * i;
    const int nn = (t & 15) * 4;
    const float4 w = *(const float4*)&W[(size_t)(k0 + kk) * Nn + n0 + nn];
    T[nn + 0][kk] = f2bf(w.x);
    T[nn + 1][kk] = f2bf(w.y);
    T[nn + 2][kk] = f2bf(w.z);
    T[nn + 3][kk] = f2bf(w.w);
  }
  __syncthreads();
#pragma unroll
  for (int i = 0; i < 4; ++i) {
    const int nn = (t >> 4) + 16 * i;
    const int kk = (t & 15) * 4;
    *(ushort4*)&WT[(size_t)(n0 + nn) * K + k0 + kk] = *(ushort4*)&T[nn][kk];
  }
}

// ---------------------------------------------------------------------------
// bf16 MFMA GEMM (as R2), epilogues now write bf16 for q/k/v.
// MODE 0: o0 = float* row-major (final @ Wout -> d_out)
// MODE 1: N=3072: col<1024 -> q bf16 (x0.125), <2048 -> k_l, else v_l
// MODE 2: N=2048: col<1024 -> k_x bf16 + RoPE(hd<32), else v_x
// ---------------------------------------------------------------------------
template <int MODE>
__global__ __launch_bounds__(256, 2) void gemm_bf16(
    const ushort* __restrict__ A, const ushort* __restrict__ B0,
    const ushort* __restrict__ B1,
    void* __restrict__ o0, ushort* __restrict__ o1, ushort* __restrict__ o2,
    const float* __restrict__ cosT, const float* __restrict__ sinT) {
  __shared__ __align__(16) ushort sm[2 * 128 * 72];
  ushort* As = sm;
  ushort* Bs = sm + 128 * 72;

  const int t = threadIdx.x;
  const int lane = t & 63;
  const int wid = t >> 6;
  const int wr = wid >> 1, wc = wid & 1;
  const int arow0 = blockIdx.x * 128;
  const int bcol0 = blockIdx.y * 128;

  const ushort* Bg;
  if (MODE == 1)
    Bg = (bcol0 < 1024) ? (B0 + (size_t)bcol0 * DIMW)
                        : (B1 + (size_t)(bcol0 - 1024) * DIMW);
  else
    Bg = B0 + (size_t)bcol0 * DIMW;
  const ushort* Ag = A + (size_t)arow0 * DIMW;

  const int srow = t >> 3;
  const int skk  = (t & 7) * 8;

  f32x4 acc[4][4];
#pragma unroll
  for (int fm = 0; fm < 4; ++fm)
#pragma unroll
    for (int fn = 0; fn < 4; ++fn) acc[fm][fn] = (f32x4)(0.0f);

  int4 ra[4], rb[4];
#pragma unroll
  for (int i = 0; i < 4; ++i) {
    const int row = i * 32 + srow;
    ra[i] = *(const int4*)(Ag + (size_t)row * DIMW + skk);
    rb[i] = *(const int4*)(Bg + (size_t)row * DIMW + skk);
  }

  const int aoff = (wr * 64 + (lane & 15)) * 72 + (lane >> 4) * 8;
  const int boff = 128 * 72 + (wc * 64 + (lane & 15)) * 72 + (lane >> 4) * 8;

  for (int kt = 0; kt < 16; ++kt) {
    __syncthreads();
#pragma unroll
    for (int i = 0; i < 4; ++i) {
      *(int4*)(As + (i * 32 + srow) * 72 + skk) = ra[i];
      *(int4*)(Bs + (i * 32 + srow) * 72 + skk) = rb[i];
    }
    __syncthreads();
    if (kt < 15) {
      const size_t ko = (size_t)(kt + 1) * 64 + skk;
#pragma unroll
      for (int i = 0; i < 4; ++i) {
        const int row = i * 32 + srow;
        ra[i] = *(const int4*)(Ag + (size_t)row * DIMW + ko);
        rb[i] = *(const int4*)(Bg + (size_t)row * DIMW + ko);
      }
    }
#pragma unroll
    for (int s = 0; s < 2; ++s) {
      bf16x8 af[4], bfr[4];
#pragma unroll
      for (int f = 0; f < 4; ++f) {
        af[f]  = *(const bf16x8*)(sm + aoff + f * 16 * 72 + s * 32);
        bfr[f] = *(const bf16x8*)(sm + boff + f * 16 * 72 + s * 32);
      }
#pragma unroll
      for (int fm = 0; fm < 4; ++fm)
#pragma unroll
        for (int fn = 0; fn < 4; ++fn)
          acc[fm][fn] = __builtin_amdgcn_mfma_f32_16x16x32_bf16(
              af[fm], bfr[fn], acc[fm][fn], 0, 0, 0);
    }
  }

  const int lr0 = (lane >> 4) * 4;
  const int lc  = lane & 15;
#pragma unroll
  for (int fm = 0; fm < 4; ++fm) {
#pragma unroll
    for (int fn = 0; fn < 4; ++fn) {
#pragma unroll
      for (int r = 0; r < 4; ++r) {
        const int row = arow0 + wr * 64 + fm * 16 + lr0 + r;
        const int col = bcol0 + wc * 64 + fn * 16 + lc;
        const float v = acc[fm][fn][r];
        if (MODE == 0) {
          ((float*)o0)[(size_t)row * DIMW + col] = v;
        } else if (MODE == 1) {
          const int b = row >> 9, m = row & 511;
          if (col < 1024) {
            ((ushort*)o0)[(size_t)((b * NH + (col >> 6)) * MLAT + m) * HDIM + (col & 63)] =
                f2bf(v * 0.125f);
          } else if (col < 2048) {
            const int c2 = col - 1024;
            o1[(size_t)((b * NH + (c2 >> 6)) * SKV + NSEQ + m) * HDIM + (c2 & 63)] = f2bf(v);
          } else {
            const int c2 = col - 2048;
            o2[(size_t)((b * NH + (c2 >> 6)) * SKV + NSEQ + m) * HDIM + (c2 & 63)] = f2bf(v);
          }
        } else {  // MODE 2
          const int b = row >> 12, pos = row & 4095;
          const float p = __shfl_xor(v, 1);
          if (col < 1024) {
            const int hd = col & 63;
            float ov = v;
            if (hd < 32) {
              const float cs = cosT[pos * 16 + (hd >> 1)];
              const float sn = sinT[pos * 16 + (hd >> 1)];
              ov = (hd & 1) ? fmaf(v, cs, p * sn) : fmaf(v, cs, -p * sn);
            }
            o1[(size_t)((b * NH + (col >> 6)) * SKV + pos) * HDIM + hd] = f2bf(ov);
          } else {
            const int c2 = col - 1024;
            o2[(size_t)((b * NH + (c2 >> 6)) * SKV + pos) * HDIM + (c2 & 63)] = f2bf(v);
          }
        }
      }
    }
  }
}

// ---------------------------------------------------------------------------
// bf16 MFMA flash attention.
// Block: 64 q-rows of one (b,h); 4 waves x 16 rows. KV tiles of 64, dbuf LDS.
// LDS (ushort): K[2][64*64] swz | VT[2][64*64] swz (VT[d][s]) | P[4][16*64] swz
// swizzle: in-row ushort offset ^= 8*(row&7)
// ---------------------------------------------------------------------------
__global__ __launch_bounds__(256) void attn_mfma(const ushort* __restrict__ q,
                                                 const ushort* __restrict__ k,
                                                 const ushort* __restrict__ v,
                                                 ushort* __restrict__ ao) {
  __shared__ __align__(16) ushort sm[20480];  // 40 KB
  const int t = threadIdx.x;
  const int l = t & 63;
  const int wid = t >> 6;
  const int qt = blockIdx.x, bh = blockIdx.y;
  const size_t kvb = (size_t)bh * SKV * HDIM;

  // Q fragments (wave's 16 rows), hoisted
  bf16x8 qf[2];
  {
    const ushort* qa = q + ((size_t)bh * MLAT + qt * 64 + wid * 16 + (l & 15)) * HDIM
                         + 8 * (l >> 4);
    qf[0] = *(const bf16x8*)(qa);
    qf[1] = *(const bf16x8*)(qa + 32);
  }

  ushort* Kb0 = sm;
  ushort* Kb1 = sm + 4096;
  ushort* Vb0 = sm + 8192;
  ushort* Vb1 = sm + 12288;
  ushort* Pw  = sm + 16384 + wid * 1024;

  // staging maps
  const int kr  = t >> 2;          // K row 0..63
  const int kc0 = t & 3;           // K chunk base (+4c)
  const int vr  = t & 63;          // V source row s
  const int vc0 = (t >> 6) * 2;    // V chunk base (+c)

  f32x4 accO[4];
#pragma unroll
  for (int fd = 0; fd < 4; ++fd) accO[fd] = (f32x4)(0.0f);
  float mrow[4] = {-1e30f, -1e30f, -1e30f, -1e30f};
  float lrow[4] = {0.0f, 0.0f, 0.0f, 0.0f};

  const ushort* kp = k + kvb;
  const ushort* vp = v + kvb;
  int4 kreg[2], vreg[2];
#pragma unroll
  for (int c = 0; c < 2; ++c) {
    kreg[c] = *(const int4*)(kp + kr * 64 + (kc0 + 4 * c) * 8);
    vreg[c] = *(const int4*)(vp + vr * 64 + (vc0 + c) * 8);
  }

  for (int kt = 0; kt < SKV / 64; ++kt) {
    ushort* Kd = (kt & 1) ? Kb1 : Kb0;
    ushort* Vd = (kt & 1) ? Vb1 : Vb0;
    // ---- write staged tile ----
#pragma unroll
    for (int c = 0; c < 2; ++c) {
      const int ch = kc0 + 4 * c;
      *(int4*)(Kd + kr * 64 + ((ch ^ (kr & 7)) * 8)) = kreg[c];
      const int vch = vc0 + c;
      const ushort* src = (const ushort*)&vreg[c];
#pragma unroll
      for (int e = 0; e < 8; ++e) {
        const int d = vch * 8 + e;
        Vd[d * 64 + (vr ^ (8 * (d & 7)))] = src[e];
      }
    }
    // ---- prefetch next tile ----
    if (kt < SKV / 64 - 1) {
      const ushort* kp2 = kp + (size_t)(kt + 1) * 64 * 64;
      const ushort* vp2 = vp + (size_t)(kt + 1) * 64 * 64;
#pragma unroll
      for (int c = 0; c < 2; ++c) {
        kreg[c] = *(const int4*)(kp2 + kr * 64 + (kc0 + 4 * c) * 8);
        vreg[c] = *(const int4*)(vp2 + vr * 64 + (vc0 + c) * 8);
      }
    }
    __syncthreads();

    // ---- QK^T: S[16 rows][64 cols] per wave ----
    f32x4 sacc[4];
#pragma unroll
    for (int fn = 0; fn < 4; ++fn) sacc[fn] = (f32x4)(0.0f);
#pragma unroll
    for (int ks = 0; ks < 2; ++ks) {
#pragma unroll
      for (int fn = 0; fn < 4; ++fn) {
        const bf16x8 kf = *(const bf16x8*)(
            Kd + (16 * fn + (l & 15)) * 64 + ((8 * (l >> 4) + 32 * ks) ^ (8 * (l & 7))));
        sacc[fn] = __builtin_amdgcn_mfma_f32_16x16x32_bf16(qf[ks], kf, sacc[fn], 0, 0, 0);
      }
    }

    // ---- online softmax (in-register; rows replicated over 16 lanes) ----
    float pvv[4][4];  // [fn][r]
    float cf[4];
#pragma unroll
    for (int r = 0; r < 4; ++r) {
      float tmax = fmaxf(fmaxf(sacc[0][r], sacc[1][r]), fmaxf(sacc[2][r], sacc[3][r]));
      tmax = fmaxf(tmax, __shfl_xor(tmax, 1));
      tmax = fmaxf(tmax, __shfl_xor(tmax, 2));
      tmax = fmaxf(tmax, __shfl_xor(tmax, 4));
      tmax = fmaxf(tmax, __shfl_xor(tmax, 8));
      const float mn = fmaxf(mrow[r], tmax);
      cf[r] = __expf(mrow[r] - mn);
      mrow[r] = mn;
      float ts = 0.0f;
#pragma unroll
      for (int fn = 0; fn < 4; ++fn) {
        const float e = __expf(sacc[fn][r] - mn);
        pvv[fn][r] = e;
        ts += e;
      }
      ts += __shfl_xor(ts, 1);
      ts += __shfl_xor(ts, 2);
      ts += __shfl_xor(ts, 4);
      ts += __shfl_xor(ts, 8);
      lrow[r] = lrow[r] * cf[r] + ts;
    }
    // rescale O
#pragma unroll
    for (int fd = 0; fd < 4; ++fd)
#pragma unroll
      for (int r = 0; r < 4; ++r) accO[fd][r] *= cf[r];

    // ---- P -> bf16 -> per-wave LDS ----
    const int rbase = 4 * (l >> 4);
#pragma unroll
    for (int fn = 0; fn < 4; ++fn)
#pragma unroll
      for (int r = 0; r < 4; ++r) {
        const int row = rbase + r;
        Pw[row * 64 + ((16 * fn + (l & 15)) ^ (8 * (row & 7)))] = f2bf(pvv[fn][r]);
      }

    // ---- PV: O += P @ V ----
#pragma unroll
    for (int ks = 0; ks < 2; ++ks) {
      const bf16x8 pa = *(const bf16x8*)(
          Pw + (l & 15) * 64 + ((8 * (l >> 4) + 32 * ks) ^ (8 * (l & 7))));
#pragma unroll
      for (int fd = 0; fd < 4; ++fd) {
        const bf16x8 vf = *(const bf16x8*)(
            Vd + (16 * fd + (l & 15)) * 64 + ((8 * (l >> 4) + 32 * ks) ^ (8 * (l & 7))));
        accO[fd] = __builtin_amdgcn_mfma_f32_16x16x32_bf16(pa, vf, accO[fd], 0, 0, 0);
      }
    }
  }

  // ---- epilogue: normalize, write bf16 ao[b][m][h*64+d] ----
  const int b = bh >> 4, h = bh & 15;
#pragma unroll
  for (int fd = 0; fd < 4; ++fd)
#pragma unroll
    for (int r = 0; r < 4; ++r) {
      const int m = qt * 64 + wid * 16 + 4 * (l >> 4) + r;
      const float val = accO[fd][r] / lrow[r];
      ao[((size_t)b * MLAT + m) * DIMW + h * HDIM + 16 * fd + (l & 15)] = f2bf(val);
    }
}

// ---------------------------------------------------------------------------
extern "C" void kernel_launch(void* const* d_in, const int* in_sizes, int n_in,
                              void* d_out, int out_size, void* d_ws, size_t ws_size,
                              hipStream_t stream) {
  const float* x    = (const float*)d_in[0];
  const float* lat  = (const float*)d_in[1];
  const float* cosT = (const float*)d_in[2];
  const float* sinT = (const float*)d_in[3];
  const float* Wq   = (const float*)d_in[4];
  const float* Wkv  = (const float*)d_in[5];
  const float* Wout = (const float*)d_in[6];
  const float* gx   = (const float*)d_in[7];
  const float* bx   = (const float*)d_in[8];
  const float* gl   = (const float*)d_in[9];
  const float* bl   = (const float*)d_in[10];
  float* out = (float*)d_out;

  // ---- workspace (all bf16/ushort) ----
  ushort* xnb   = (ushort*)d_ws;                        // 8192*1024
  ushort* lnb   = xnb   + (size_t)8192 * 1024;          // 1024*1024
  ushort* WqT   = lnb   + (size_t)1024 * 1024;          // 1024*1024
  ushort* WkvT  = WqT   + (size_t)1024 * 1024;          // 2048*1024
  ushort* WoutT = WkvT  + (size_t)2048 * 1024;          // 1024*1024
  ushort* qwb   = WoutT + (size_t)1024 * 1024;          // 2*16*512*64
  ushort* kwb   = qwb   + (size_t)NB * NH * MLAT * HDIM;// 2*16*4608*64
  ushort* vwb   = kwb   + (size_t)NB * NH * SKV * HDIM;
  ushort* aob   = vwb   + (size_t)NB * NH * SKV * HDIM; // 1024*1024
  // ~69 MB total

  ln_kernel<<<dim3(NB * NSEQ), dim3(256), 0, stream>>>(x, gx, bx, xnb);
  ln_kernel<<<dim3(NB * MLAT), dim3(256), 0, stream>>>(lat, gl, bl, lnb);

  tcast_kernel<<<dim3(16, 16), dim3(256), 0, stream>>>(Wq,   WqT,   DIMW, 1024);
  tcast_kernel<<<dim3(32, 16), dim3(256), 0, stream>>>(Wkv,  WkvT,  DIMW, 2048);
  tcast_kernel<<<dim3(16, 16), dim3(256), 0, stream>>>(Wout, WoutT, DIMW, 1024);

  // fused: [q | k_l | v_l] = ln @ [Wq | Wkv]   (M=1024, N=3072)
  gemm_bf16<1><<<dim3(8, 24), dim3(256), 0, stream>>>(
      lnb, WqT, WkvT, qwb, kwb, vwb, nullptr, nullptr);
  // kv_x = xn @ Wkv (M=8192, N=2048), RoPE on k
  gemm_bf16<2><<<dim3(64, 16), dim3(256), 0, stream>>>(
      xnb, WkvT, nullptr, nullptr, kwb, vwb, cosT, sinT);

  attn_mfma<<<dim3(8, 32), dim3(256), 0, stream>>>(qwb, kwb, vwb, aob);

  // out = ao @ Wout (M=1024, N=1024)
  gemm_bf16<0><<<dim3(8, 8), dim3(256), 0, stream>>>(
      aob, WoutT, nullptr, out, nullptr, nullptr, nullptr, nullptr);
}

// Round 11
// 535.754 us; speedup vs baseline: 2.2784x; 1.0283x over previous
//
#include <hip/hip_runtime.h>
#include <hip/hip_bf16.h>

#define DIMW 1024
#define NB 2
#define NSEQ 4096
#define MLAT 512
#define NH 16
#define HDIM 64
#define SKV 4608   // NSEQ + MLAT
#define LNEPS 1e-5f

typedef __attribute__((ext_vector_type(8))) short bf16x8;
typedef __attribute__((ext_vector_type(4))) float f32x4;

static __device__ __forceinline__ ushort f2bf(float f) {
  __hip_bfloat16 h = __float2bfloat16(f);
  return *reinterpret_cast<ushort*>(&h);
}

// ---------------------------------------------------------------------------
// LayerNorm: one block per row of 1024 floats -> bf16 out.
// ---------------------------------------------------------------------------
__global__ __launch_bounds__(256) void ln_kernel(const float* __restrict__ in,
                                                 const float* __restrict__ g,
                                                 const float* __restrict__ bb,
                                                 ushort* __restrict__ out) {
  const int row = blockIdx.x;
  const int tid = threadIdx.x;
  const float4 x = reinterpret_cast<const float4*>(in + (size_t)row * DIMW)[tid];
  float s  = x.x + x.y + x.z + x.w;
  float ss = x.x * x.x + x.y * x.y + x.z * x.z + x.w * x.w;
#pragma unroll
  for (int off = 1; off < 64; off <<= 1) {
    s  += __shfl_xor(s, off);
    ss += __shfl_xor(ss, off);
  }
  __shared__ float red[8];
  const int wid = tid >> 6;
  if ((tid & 63) == 0) { red[wid] = s; red[4 + wid] = ss; }
  __syncthreads();
  const float S  = red[0] + red[1] + red[2] + red[3];
  const float SS = red[4] + red[5] + red[6] + red[7];
  const float mu  = S * (1.0f / DIMW);
  const float var = SS * (1.0f / DIMW) - mu * mu;
  const float rv  = rsqrtf(var + LNEPS);
  const float4 g4 = reinterpret_cast<const float4*>(g)[tid];
  const float4 b4 = reinterpret_cast<const float4*>(bb)[tid];
  ushort4 o = make_ushort4(f2bf((x.x - mu) * rv * g4.x + b4.x),
                           f2bf((x.y - mu) * rv * g4.y + b4.y),
                           f2bf((x.z - mu) * rv * g4.z + b4.z),
                           f2bf((x.w - mu) * rv * g4.w + b4.w));
  *reinterpret_cast<ushort4*>(out + (size_t)row * DIMW + tid * 4) = o;
}

// ---------------------------------------------------------------------------
// Transpose + cast: W [K][Nn] f32 -> WT [Nn][K] bf16. 64x64 tiles.
// ---------------------------------------------------------------------------
__global__ __launch_bounds__(256) void tcast_kernel(const float* __restrict__ W,
                                                    ushort* __restrict__ WT,
                                                    int K, int Nn) {
  __shared__ __align__(16) ushort T[64][72];
  const int t = threadIdx.x;
  const int n0 = blockIdx.x * 64, k0 = blockIdx.y * 64;
#pragma unroll
  for (int i = 0; i < 4; ++i) {
    const int kk = (t >> 4) + 16 * i;
    const int nn = (t & 15) * 4;
    const float4 w = *(const float4*)&W[(size_t)(k0 + kk) * Nn + n0 + nn];
    T[nn + 0][kk] = f2bf(w.x);
    T[nn + 1][kk] = f2bf(w.y);
    T[nn + 2][kk] = f2bf(w.z);
    T[nn + 3][kk] = f2bf(w.w);
  }
  __syncthreads();
#pragma unroll
  for (int i = 0; i < 4; ++i) {
    const int nn = (t >> 4) + 16 * i;
    const int kk = (t & 15) * 4;
    *(ushort4*)&WT[(size_t)(n0 + nn) * K + k0 + kk] = *(ushort4*)&T[nn][kk];
  }
}

// ---------------------------------------------------------------------------
// bf16 MFMA GEMM. 128x128 tile, BK=64, 4 waves.
// MODE 0: o0 = float* row-major (final @ Wout -> d_out), direct stores.
// MODE 1: N=3072: col<1024 -> q bf16 (x0.125), <2048 -> k_l, else v_l
// MODE 2: N=2048: col<1024 -> k_x bf16 + RoPE(hd<32), else v_x
// Scatter modes restage through LDS -> coalesced int4 row stores.
// ---------------------------------------------------------------------------
template <int MODE>
__global__ __launch_bounds__(256, 2) void gemm_bf16(
    const ushort* __restrict__ A, const ushort* __restrict__ B0,
    const ushort* __restrict__ B1,
    void* __restrict__ o0, ushort* __restrict__ o1, ushort* __restrict__ o2,
    const float* __restrict__ cosT, const float* __restrict__ sinT) {
  __shared__ __align__(16) ushort sm[2 * 128 * 72];  // 36 KB
  ushort* As = sm;
  ushort* Bs = sm + 128 * 72;

  const int t = threadIdx.x;
  const int lane = t & 63;
  const int wid = t >> 6;
  const int wr = wid >> 1, wc = wid & 1;
  const int arow0 = blockIdx.x * 128;
  const int bcol0 = blockIdx.y * 128;

  const ushort* Bg;
  if (MODE == 1)
    Bg = (bcol0 < 1024) ? (B0 + (size_t)bcol0 * DIMW)
                        : (B1 + (size_t)(bcol0 - 1024) * DIMW);
  else
    Bg = B0 + (size_t)bcol0 * DIMW;
  const ushort* Ag = A + (size_t)arow0 * DIMW;

  const int srow = t >> 3;
  const int skk  = (t & 7) * 8;

  f32x4 acc[4][4];
#pragma unroll
  for (int fm = 0; fm < 4; ++fm)
#pragma unroll
    for (int fn = 0; fn < 4; ++fn) acc[fm][fn] = (f32x4)(0.0f);

  int4 ra[4], rb[4];
#pragma unroll
  for (int i = 0; i < 4; ++i) {
    const int row = i * 32 + srow;
    ra[i] = *(const int4*)(Ag + (size_t)row * DIMW + skk);
    rb[i] = *(const int4*)(Bg + (size_t)row * DIMW + skk);
  }

  const int aoff = (wr * 64 + (lane & 15)) * 72 + (lane >> 4) * 8;
  const int boff = 128 * 72 + (wc * 64 + (lane & 15)) * 72 + (lane >> 4) * 8;

  for (int kt = 0; kt < 16; ++kt) {
    __syncthreads();
#pragma unroll
    for (int i = 0; i < 4; ++i) {
      *(int4*)(As + (i * 32 + srow) * 72 + skk) = ra[i];
      *(int4*)(Bs + (i * 32 + srow) * 72 + skk) = rb[i];
    }
    __syncthreads();
    if (kt < 15) {
      const size_t ko = (size_t)(kt + 1) * 64 + skk;
#pragma unroll
      for (int i = 0; i < 4; ++i) {
        const int row = i * 32 + srow;
        ra[i] = *(const int4*)(Ag + (size_t)row * DIMW + ko);
        rb[i] = *(const int4*)(Bg + (size_t)row * DIMW + ko);
      }
    }
#pragma unroll
    for (int s = 0; s < 2; ++s) {
      bf16x8 af[4], bfr[4];
#pragma unroll
      for (int f = 0; f < 4; ++f) {
        af[f]  = *(const bf16x8*)(sm + aoff + f * 16 * 72 + s * 32);
        bfr[f] = *(const bf16x8*)(sm + boff + f * 16 * 72 + s * 32);
      }
#pragma unroll
      for (int fm = 0; fm < 4; ++fm)
#pragma unroll
        for (int fn = 0; fn < 4; ++fn)
          acc[fm][fn] = __builtin_amdgcn_mfma_f32_16x16x32_bf16(
              af[fm], bfr[fn], acc[fm][fn], 0, 0, 0);
    }
  }

  // ---------------- epilogue ----------------
  const int lr0 = (lane >> 4) * 4;
  const int lc  = lane & 15;

  if (MODE == 0) {
    // direct float row-major stores
#pragma unroll
    for (int fm = 0; fm < 4; ++fm)
#pragma unroll
      for (int fn = 0; fn < 4; ++fn)
#pragma unroll
        for (int r = 0; r < 4; ++r) {
          const int row = arow0 + wr * 64 + fm * 16 + lr0 + r;
          const int col = bcol0 + wc * 64 + fn * 16 + lc;
          ((float*)o0)[(size_t)row * DIMW + col] = acc[fm][fn][r];
        }
  } else {
    // restage through LDS (bf16 [128][136]) then coalesced int4 stores
    __syncthreads();  // all fragment reads of sm are done
    ushort* Es = sm;  // 128*136*2 = 34816 B <= 36864 B
#pragma unroll
    for (int fm = 0; fm < 4; ++fm)
#pragma unroll
      for (int fn = 0; fn < 4; ++fn)
#pragma unroll
        for (int r = 0; r < 4; ++r) {
          const int rl = wr * 64 + fm * 16 + lr0 + r;
          const int cl = wc * 64 + fn * 16 + lc;
          const int row = arow0 + rl;
          const int col = bcol0 + cl;
          float v = acc[fm][fn][r];
          const float p = __shfl_xor(v, 1);  // partner col (pre-transform)
          if (MODE == 1) {
            if (col < 1024) v *= 0.125f;  // q scale
          } else {  // MODE 2: RoPE on k_x hd<32
            if (col < 1024) {
              const int hd = col & 63;
              if (hd < 32) {
                const int pos = row & 4095;
                const float cs = cosT[pos * 16 + (hd >> 1)];
                const float sn = sinT[pos * 16 + (hd >> 1)];
                v = (hd & 1) ? fmaf(v, cs, p * sn) : fmaf(v, cs, -p * sn);
              }
            }
          }
          Es[rl * 136 + cl] = f2bf(v);
        }
    __syncthreads();
    // 8 passes x 256 threads x int4: each 16-lane group writes two full
    // 128B head-rows -> fully coalesced segments.
#pragma unroll
    for (int p8 = 0; p8 < 8; ++p8) {
      const int idx = p8 * 256 + t;
      const int rl  = idx >> 4;        // 0..127 local row
      const int c8  = idx & 15;        // 16B chunk within row
      const int row = arow0 + rl;
      const int col0 = bcol0 + c8 * 8;
      const int4 val = *(const int4*)(Es + rl * 136 + c8 * 8);
      ushort* dst;
      if (MODE == 1) {
        const int b = row >> 9, m = row & 511;
        if (col0 < 1024) {
          dst = (ushort*)o0 +
                (size_t)((b * NH + (col0 >> 6)) * MLAT + m) * HDIM + (col0 & 63);
        } else if (col0 < 2048) {
          const int c2 = col0 - 1024;
          dst = o1 + (size_t)((b * NH + (c2 >> 6)) * SKV + NSEQ + m) * HDIM + (c2 & 63);
        } else {
          const int c2 = col0 - 2048;
          dst = o2 + (size_t)((b * NH + (c2 >> 6)) * SKV + NSEQ + m) * HDIM + (c2 & 63);
        }
      } else {  // MODE 2
        const int b = row >> 12, pos = row & 4095;
        if (col0 < 1024) {
          dst = o1 + (size_t)((b * NH + (col0 >> 6)) * SKV + pos) * HDIM + (col0 & 63);
        } else {
          const int c2 = col0 - 1024;
          dst = o2 + (size_t)((b * NH + (c2 >> 6)) * SKV + pos) * HDIM + (c2 & 63);
        }
      }
      *(int4*)dst = val;
    }
  }
}

// ---------------------------------------------------------------------------
// bf16 MFMA flash attention (unchanged from R4 — verified correct).
// ---------------------------------------------------------------------------
__global__ __launch_bounds__(256) void attn_mfma(const ushort* __restrict__ q,
                                                 const ushort* __restrict__ k,
                                                 const ushort* __restrict__ v,
                                                 ushort* __restrict__ ao) {
  __shared__ __align__(16) ushort sm[20480];  // 40 KB
  const int t = threadIdx.x;
  const int l = t & 63;
  const int wid = t >> 6;
  const int qt = blockIdx.x, bh = blockIdx.y;
  const size_t kvb = (size_t)bh * SKV * HDIM;

  bf16x8 qf[2];
  {
    const ushort* qa = q + ((size_t)bh * MLAT + qt * 64 + wid * 16 + (l & 15)) * HDIM
                         + 8 * (l >> 4);
    qf[0] = *(const bf16x8*)(qa);
    qf[1] = *(const bf16x8*)(qa + 32);
  }

  ushort* Kb0 = sm;
  ushort* Kb1 = sm + 4096;
  ushort* Vb0 = sm + 8192;
  ushort* Vb1 = sm + 12288;
  ushort* Pw  = sm + 16384 + wid * 1024;

  const int kr  = t >> 2;
  const int kc0 = t & 3;
  const int vr  = t & 63;
  const int vc0 = (t >> 6) * 2;

  f32x4 accO[4];
#pragma unroll
  for (int fd = 0; fd < 4; ++fd) accO[fd] = (f32x4)(0.0f);
  float mrow[4] = {-1e30f, -1e30f, -1e30f, -1e30f};
  float lrow[4] = {0.0f, 0.0f, 0.0f, 0.0f};

  const ushort* kp = k + kvb;
  const ushort* vp = v + kvb;
  int4 kreg[2], vreg[2];
#pragma unroll
  for (int c = 0; c < 2; ++c) {
    kreg[c] = *(const int4*)(kp + kr * 64 + (kc0 + 4 * c) * 8);
    vreg[c] = *(const int4*)(vp + vr * 64 + (vc0 + c) * 8);
  }

  for (int kt = 0; kt < SKV / 64; ++kt) {
    ushort* Kd = (kt & 1) ? Kb1 : Kb0;
    ushort* Vd = (kt & 1) ? Vb1 : Vb0;
#pragma unroll
    for (int c = 0; c < 2; ++c) {
      const int ch = kc0 + 4 * c;
      *(int4*)(Kd + kr * 64 + ((ch ^ (kr & 7)) * 8)) = kreg[c];
      const int vch = vc0 + c;
      const ushort* src = (const ushort*)&vreg[c];
#pragma unroll
      for (int e = 0; e < 8; ++e) {
        const int d = vch * 8 + e;
        Vd[d * 64 + (vr ^ (8 * (d & 7)))] = src[e];
      }
    }
    if (kt < SKV / 64 - 1) {
      const ushort* kp2 = kp + (size_t)(kt + 1) * 64 * 64;
      const ushort* vp2 = vp + (size_t)(kt + 1) * 64 * 64;
#pragma unroll
      for (int c = 0; c < 2; ++c) {
        kreg[c] = *(const int4*)(kp2 + kr * 64 + (kc0 + 4 * c) * 8);
        vreg[c] = *(const int4*)(vp2 + vr * 64 + (vc0 + c) * 8);
      }
    }
    __syncthreads();

    f32x4 sacc[4];
#pragma unroll
    for (int fn = 0; fn < 4; ++fn) sacc[fn] = (f32x4)(0.0f);
#pragma unroll
    for (int ks = 0; ks < 2; ++ks) {
#pragma unroll
      for (int fn = 0; fn < 4; ++fn) {
        const bf16x8 kf = *(const bf16x8*)(
            Kd + (16 * fn + (l & 15)) * 64 + ((8 * (l >> 4) + 32 * ks) ^ (8 * (l & 7))));
        sacc[fn] = __builtin_amdgcn_mfma_f32_16x16x32_bf16(qf[ks], kf, sacc[fn], 0, 0, 0);
      }
    }

    float pvv[4][4];
    float cf[4];
#pragma unroll
    for (int r = 0; r < 4; ++r) {
      float tmax = fmaxf(fmaxf(sacc[0][r], sacc[1][r]), fmaxf(sacc[2][r], sacc[3][r]));
      tmax = fmaxf(tmax, __shfl_xor(tmax, 1));
      tmax = fmaxf(tmax, __shfl_xor(tmax, 2));
      tmax = fmaxf(tmax, __shfl_xor(tmax, 4));
      tmax = fmaxf(tmax, __shfl_xor(tmax, 8));
      const float mn = fmaxf(mrow[r], tmax);
      cf[r] = __expf(mrow[r] - mn);
      mrow[r] = mn;
      float ts = 0.0f;
#pragma unroll
      for (int fn = 0; fn < 4; ++fn) {
        const float e = __expf(sacc[fn][r] - mn);
        pvv[fn][r] = e;
        ts += e;
      }
      ts += __shfl_xor(ts, 1);
      ts += __shfl_xor(ts, 2);
      ts += __shfl_xor(ts, 4);
      ts += __shfl_xor(ts, 8);
      lrow[r] = lrow[r] * cf[r] + ts;
    }
#pragma unroll
    for (int fd = 0; fd < 4; ++fd)
#pragma unroll
      for (int r = 0; r < 4; ++r) accO[fd][r] *= cf[r];

    const int rbase = 4 * (l >> 4);
#pragma unroll
    for (int fn = 0; fn < 4; ++fn)
#pragma unroll
      for (int r = 0; r < 4; ++r) {
        const int row = rbase + r;
        Pw[row * 64 + ((16 * fn + (l & 15)) ^ (8 * (row & 7)))] = f2bf(pvv[fn][r]);
      }

#pragma unroll
    for (int ks = 0; ks < 2; ++ks) {
      const bf16x8 pa = *(const bf16x8*)(
          Pw + (l & 15) * 64 + ((8 * (l >> 4) + 32 * ks) ^ (8 * (l & 7))));
#pragma unroll
      for (int fd = 0; fd < 4; ++fd) {
        const bf16x8 vf = *(const bf16x8*)(
            Vd + (16 * fd + (l & 15)) * 64 + ((8 * (l >> 4) + 32 * ks) ^ (8 * (l & 7))));
        accO[fd] = __builtin_amdgcn_mfma_f32_16x16x32_bf16(pa, vf, accO[fd], 0, 0, 0);
      }
    }
  }

  const int b = bh >> 4, h = bh & 15;
#pragma unroll
  for (int fd = 0; fd < 4; ++fd)
#pragma unroll
    for (int r = 0; r < 4; ++r) {
      const int m = qt * 64 + wid * 16 + 4 * (l >> 4) + r;
      const float val = accO[fd][r] / lrow[r];
      ao[((size_t)b * MLAT + m) * DIMW + h * HDIM + 16 * fd + (l & 15)] = f2bf(val);
    }
}

// ---------------------------------------------------------------------------
extern "C" void kernel_launch(void* const* d_in, const int* in_sizes, int n_in,
                              void* d_out, int out_size, void* d_ws, size_t ws_size,
                              hipStream_t stream) {
  const float* x    = (const float*)d_in[0];
  const float* lat  = (const float*)d_in[1];
  const float* cosT = (const float*)d_in[2];
  const float* sinT = (const float*)d_in[3];
  const float* Wq   = (const float*)d_in[4];
  const float* Wkv  = (const float*)d_in[5];
  const float* Wout = (const float*)d_in[6];
  const float* gx   = (const float*)d_in[7];
  const float* bx   = (const float*)d_in[8];
  const float* gl   = (const float*)d_in[9];
  const float* bl   = (const float*)d_in[10];
  float* out = (float*)d_out;

  ushort* xnb   = (ushort*)d_ws;                        // 8192*1024
  ushort* lnb   = xnb   + (size_t)8192 * 1024;          // 1024*1024
  ushort* WqT   = lnb   + (size_t)1024 * 1024;          // 1024*1024
  ushort* WkvT  = WqT   + (size_t)1024 * 1024;          // 2048*1024
  ushort* WoutT = WkvT  + (size_t)2048 * 1024;          // 1024*1024
  ushort* qwb   = WoutT + (size_t)1024 * 1024;          // 2*16*512*64
  ushort* kwb   = qwb   + (size_t)NB * NH * MLAT * HDIM;// 2*16*4608*64
  ushort* vwb   = kwb   + (size_t)NB * NH * SKV * HDIM;
  ushort* aob   = vwb   + (size_t)NB * NH * SKV * HDIM; // 1024*1024

  ln_kernel<<<dim3(NB * NSEQ), dim3(256), 0, stream>>>(x, gx, bx, xnb);
  ln_kernel<<<dim3(NB * MLAT), dim3(256), 0, stream>>>(lat, gl, bl, lnb);

  tcast_kernel<<<dim3(16, 16), dim3(256), 0, stream>>>(Wq,   WqT,   DIMW, 1024);
  tcast_kernel<<<dim3(32, 16), dim3(256), 0, stream>>>(Wkv,  WkvT,  DIMW, 2048);
  tcast_kernel<<<dim3(16, 16), dim3(256), 0, stream>>>(Wout, WoutT, DIMW, 1024);

  // fused: [q | k_l | v_l] = ln @ [Wq | Wkv]   (M=1024, N=3072)
  gemm_bf16<1><<<dim3(8, 24), dim3(256), 0, stream>>>(
      lnb, WqT, WkvT, qwb, kwb, vwb, nullptr, nullptr);
  // kv_x = xn @ Wkv (M=8192, N=2048), RoPE on k
  gemm_bf16<2><<<dim3(64, 16), dim3(256), 0, stream>>>(
      xnb, WkvT, nullptr, nullptr, kwb, vwb, cosT, sinT);

  attn_mfma<<<dim3(8, 32), dim3(256), 0, stream>>>(qwb, kwb, vwb, aob);

  // out = ao @ Wout (M=1024, N=1024)
  gemm_bf16<0><<<dim3(8, 8), dim3(256), 0, stream>>>(
      aob, WoutT, nullptr, out, nullptr, nullptr, nullptr, nullptr);
}

// Round 14
// 332.001 us; speedup vs baseline: 3.6768x; 1.6137x over previous
//
#include <hip/hip_runtime.h>
#include <hip/hip_bf16.h>

#define DIMW 1024
#define NB 2
#define NSEQ 4096
#define MLAT 512
#define NH 16
#define HDIM 64
#define SKV 4608   // NSEQ + MLAT
#define LNEPS 1e-5f

typedef __attribute__((ext_vector_type(8))) short bf16x8;
typedef __attribute__((ext_vector_type(4))) float f32x4;

static __device__ __forceinline__ ushort f2bf(float f) {
  __hip_bfloat16 h = __float2bfloat16(f);
  return *reinterpret_cast<ushort*>(&h);
}

// async global->LDS, 16B per lane; LDS dest must be wave-uniform base + lane*16
#define GLOAD_LDS16(gp, lp)                                                    \
  __builtin_amdgcn_global_load_lds(                                            \
      (const __attribute__((address_space(1))) void*)(gp),                     \
      (__attribute__((address_space(3))) void*)(lp), 16, 0, 0)

// ---------------------------------------------------------------------------
// LayerNorm: one block per row of 1024 floats -> bf16 out.
// ---------------------------------------------------------------------------
__global__ __launch_bounds__(256) void ln_kernel(const float* __restrict__ in,
                                                 const float* __restrict__ g,
                                                 const float* __restrict__ bb,
                                                 ushort* __restrict__ out) {
  const int row = blockIdx.x;
  const int tid = threadIdx.x;
  const float4 x = reinterpret_cast<const float4*>(in + (size_t)row * DIMW)[tid];
  float s  = x.x + x.y + x.z + x.w;
  float ss = x.x * x.x + x.y * x.y + x.z * x.z + x.w * x.w;
#pragma unroll
  for (int off = 1; off < 64; off <<= 1) {
    s  += __shfl_xor(s, off);
    ss += __shfl_xor(ss, off);
  }
  __shared__ float red[8];
  const int wid = tid >> 6;
  if ((tid & 63) == 0) { red[wid] = s; red[4 + wid] = ss; }
  __syncthreads();
  const float S  = red[0] + red[1] + red[2] + red[3];
  const float SS = red[4] + red[5] + red[6] + red[7];
  const float mu  = S * (1.0f / DIMW);
  const float var = SS * (1.0f / DIMW) - mu * mu;
  const float rv  = rsqrtf(var + LNEPS);
  const float4 g4 = reinterpret_cast<const float4*>(g)[tid];
  const float4 b4 = reinterpret_cast<const float4*>(bb)[tid];
  ushort4 o = make_ushort4(f2bf((x.x - mu) * rv * g4.x + b4.x),
                           f2bf((x.y - mu) * rv * g4.y + b4.y),
                           f2bf((x.z - mu) * rv * g4.z + b4.z),
                           f2bf((x.w - mu) * rv * g4.w + b4.w));
  *reinterpret_cast<ushort4*>(out + (size_t)row * DIMW + tid * 4) = o;
}

// ---------------------------------------------------------------------------
// Transpose + cast: W [K][Nn] f32 -> WT [Nn][K] bf16. 64x64 tiles.
// ---------------------------------------------------------------------------
__global__ __launch_bounds__(256) void tcast_kernel(const float* __restrict__ W,
                                                    ushort* __restrict__ WT,
                                                    int K, int Nn) {
  __shared__ __align__(16) ushort T[64][72];
  const int t = threadIdx.x;
  const int n0 = blockIdx.x * 64, k0 = blockIdx.y * 64;
#pragma unroll
  for (int i = 0; i < 4; ++i) {
    const int kk = (t >> 4) + 16 * i;
    const int nn = (t & 15) * 4;
    const float4 w = *(const float4*)&W[(size_t)(k0 + kk) * Nn + n0 + nn];
    T[nn + 0][kk] = f2bf(w.x);
    T[nn + 1][kk] = f2bf(w.y);
    T[nn + 2][kk] = f2bf(w.z);
    T[nn + 3][kk] = f2bf(w.w);
  }
  __syncthreads();
#pragma unroll
  for (int i = 0; i < 4; ++i) {
    const int nn = (t >> 4) + 16 * i;
    const int kk = (t & 15) * 4;
    *(ushort4*)&WT[(size_t)(n0 + nn) * K + k0 + kk] = *(ushort4*)&T[nn][kk];
  }
}

// ---------------------------------------------------------------------------
// bf16 MFMA GEMM, m97 staging: linear LDS [128][64], global_load_lds w=16,
// 2 barriers per K-step. 128x128 tile, BK=64, 4 waves.
// MODE 0: o0 = float* row-major (final @ Wout -> d_out), direct stores.
// MODE 1: N=3072: col<1024 -> q bf16 (x0.125), <2048 -> k_l, else v_l
// MODE 2: N=2048: col<1024 -> k_x bf16 + RoPE(hd<32), else v_x
// Scatter modes restage through LDS -> coalesced int4 row stores.
// ---------------------------------------------------------------------------
template <int MODE>
__global__ __launch_bounds__(256, 2) void gemm_bf16(
    const ushort* __restrict__ A, const ushort* __restrict__ B0,
    const ushort* __restrict__ B1,
    void* __restrict__ o0, ushort* __restrict__ o1, ushort* __restrict__ o2,
    const float* __restrict__ cosT, const float* __restrict__ sinT) {
  // staging: As = sm[0..8191], Bs = sm[8192..16383] (linear, pitch 64 shorts)
  // epilogue restage Es aliases sm, pitch 136, 128*136 = 17408 shorts
  __shared__ __align__(16) ushort sm[17408];  // 34816 B
  ushort* As = sm;
  ushort* Bs = sm + 8192;

  const int t = threadIdx.x;
  const int lane = t & 63;
  const int wid = t >> 6;
  const int wr = wid >> 1, wc = wid & 1;
  const int arow0 = blockIdx.x * 128;
  const int bcol0 = blockIdx.y * 128;

  const ushort* Bg;
  if (MODE == 1)
    Bg = (bcol0 < 1024) ? (B0 + (size_t)bcol0 * DIMW)
                        : (B1 + (size_t)(bcol0 - 1024) * DIMW);
  else
    Bg = B0 + (size_t)bcol0 * DIMW;
  const ushort* Ag = A + (size_t)arow0 * DIMW;

  // staging map: per round r (0..3), this thread covers LDS shorts
  //   off = r*2048 + wid*512 + lane*8   (bytes: wave-uniform + lane*16)
  // row = off>>6 (pitch 64), col = (lane&7)*8
  const int srow_base = wid * 8;          // + r*32 + (lane>>3)
  const int scol = (lane & 7) * 8;

  f32x4 acc[4][4];
#pragma unroll
  for (int fm = 0; fm < 4; ++fm)
#pragma unroll
    for (int fn = 0; fn < 4; ++fn) acc[fm][fn] = (f32x4)(0.0f);

  const int aoff = (wr * 64 + (lane & 15)) * 64 + (lane >> 4) * 8;
  const int boff = 8192 + (wc * 64 + (lane & 15)) * 64 + (lane >> 4) * 8;

  for (int kt = 0; kt < 16; ++kt) {
    __syncthreads();  // previous tile's fragment reads complete
#pragma unroll
    for (int r = 0; r < 4; ++r) {
      const int off  = r * 2048 + wid * 512 + lane * 8;   // shorts
      const int row  = r * 32 + srow_base + (lane >> 3);
      const size_t gofs = (size_t)row * DIMW + kt * 64 + scol;
      GLOAD_LDS16(Ag + gofs, As + off);
      GLOAD_LDS16(Bg + gofs, Bs + off);
    }
    __syncthreads();  // drains vmcnt -> tile resident in LDS
#pragma unroll
    for (int s = 0; s < 2; ++s) {
      bf16x8 af[4], bfr[4];
#pragma unroll
      for (int f = 0; f < 4; ++f) {
        af[f]  = *(const bf16x8*)(sm + aoff + f * 16 * 64 + s * 32);
        bfr[f] = *(const bf16x8*)(sm + boff + f * 16 * 64 + s * 32);
      }
#pragma unroll
      for (int fm = 0; fm < 4; ++fm)
#pragma unroll
        for (int fn = 0; fn < 4; ++fn)
          acc[fm][fn] = __builtin_amdgcn_mfma_f32_16x16x32_bf16(
              af[fm], bfr[fn], acc[fm][fn], 0, 0, 0);
    }
  }

  // ---------------- epilogue ----------------
  const int lr0 = (lane >> 4) * 4;
  const int lc  = lane & 15;

  if (MODE == 0) {
    // direct float row-major stores
#pragma unroll
    for (int fm = 0; fm < 4; ++fm)
#pragma unroll
      for (int fn = 0; fn < 4; ++fn)
#pragma unroll
        for (int r = 0; r < 4; ++r) {
          const int row = arow0 + wr * 64 + fm * 16 + lr0 + r;
          const int col = bcol0 + wc * 64 + fn * 16 + lc;
          ((float*)o0)[(size_t)row * DIMW + col] = acc[fm][fn][r];
        }
  } else {
    // restage through LDS (bf16 [128][136]) then coalesced int4 stores
    __syncthreads();  // all fragment reads of sm are done
    ushort* Es = sm;  // 128*136 = 17408 shorts, fits sm exactly
#pragma unroll
    for (int fm = 0; fm < 4; ++fm)
#pragma unroll
      for (int fn = 0; fn < 4; ++fn)
#pragma unroll
        for (int r = 0; r < 4; ++r) {
          const int rl = wr * 64 + fm * 16 + lr0 + r;
          const int cl = wc * 64 + fn * 16 + lc;
          const int row = arow0 + rl;
          const int col = bcol0 + cl;
          float v = acc[fm][fn][r];
          const float p = __shfl_xor(v, 1);  // partner col (pre-transform)
          if (MODE == 1) {
            if (col < 1024) v *= 0.125f;  // q scale
          } else {  // MODE 2: RoPE on k_x hd<32
            if (col < 1024) {
              const int hd = col & 63;
              if (hd < 32) {
                const int pos = row & 4095;
                const float cs = cosT[pos * 16 + (hd >> 1)];
                const float sn = sinT[pos * 16 + (hd >> 1)];
                v = (hd & 1) ? fmaf(v, cs, p * sn) : fmaf(v, cs, -p * sn);
              }
            }
          }
          Es[rl * 136 + cl] = f2bf(v);
        }
    __syncthreads();
    // 8 passes x 256 threads x int4: each 8-lane group writes one full
    // 128B head-row segment -> fully coalesced.
#pragma unroll
    for (int p8 = 0; p8 < 8; ++p8) {
      const int idx = p8 * 256 + t;
      const int rl  = idx >> 4;        // 0..127 local row
      const int c8  = idx & 15;        // 16B chunk within row
      const int row = arow0 + rl;
      const int col0 = bcol0 + c8 * 8;
      const int4 val = *(const int4*)(Es + rl * 136 + c8 * 8);
      ushort* dst;
      if (MODE == 1) {
        const int b = row >> 9, m = row & 511;
        if (col0 < 1024) {
          dst = (ushort*)o0 +
                (size_t)((b * NH + (col0 >> 6)) * MLAT + m) * HDIM + (col0 & 63);
        } else if (col0 < 2048) {
          const int c2 = col0 - 1024;
          dst = o1 + (size_t)((b * NH + (c2 >> 6)) * SKV + NSEQ + m) * HDIM + (c2 & 63);
        } else {
          const int c2 = col0 - 2048;
          dst = o2 + (size_t)((b * NH + (c2 >> 6)) * SKV + NSEQ + m) * HDIM + (c2 & 63);
        }
      } else {  // MODE 2
        const int b = row >> 12, pos = row & 4095;
        if (col0 < 1024) {
          dst = o1 + (size_t)((b * NH + (col0 >> 6)) * SKV + pos) * HDIM + (col0 & 63);
        } else {
          const int c2 = col0 - 1024;
          dst = o2 + (size_t)((b * NH + (c2 >> 6)) * SKV + pos) * HDIM + (c2 & 63);
        }
      }
      *(int4*)dst = val;
    }
  }
}

// ---------------------------------------------------------------------------
// bf16 MFMA flash attention (unchanged from R4 — verified correct).
// ---------------------------------------------------------------------------
__global__ __launch_bounds__(256) void attn_mfma(const ushort* __restrict__ q,
                                                 const ushort* __restrict__ k,
                                                 const ushort* __restrict__ v,
                                                 ushort* __restrict__ ao) {
  __shared__ __align__(16) ushort sm[20480];  // 40 KB
  const int t = threadIdx.x;
  const int l = t & 63;
  const int wid = t >> 6;
  const int qt = blockIdx.x, bh = blockIdx.y;
  const size_t kvb = (size_t)bh * SKV * HDIM;

  bf16x8 qf[2];
  {
    const ushort* qa = q + ((size_t)bh * MLAT + qt * 64 + wid * 16 + (l & 15)) * HDIM
                         + 8 * (l >> 4);
    qf[0] = *(const bf16x8*)(qa);
    qf[1] = *(const bf16x8*)(qa + 32);
  }

  ushort* Kb0 = sm;
  ushort* Kb1 = sm + 4096;
  ushort* Vb0 = sm + 8192;
  ushort* Vb1 = sm + 12288;
  ushort* Pw  = sm + 16384 + wid * 1024;

  const int kr  = t >> 2;
  const int kc0 = t & 3;
  const int vr  = t & 63;
  const int vc0 = (t >> 6) * 2;

  f32x4 accO[4];
#pragma unroll
  for (int fd = 0; fd < 4; ++fd) accO[fd] = (f32x4)(0.0f);
  float mrow[4] = {-1e30f, -1e30f, -1e30f, -1e30f};
  float lrow[4] = {0.0f, 0.0f, 0.0f, 0.0f};

  const ushort* kp = k + kvb;
  const ushort* vp = v + kvb;
  int4 kreg[2], vreg[2];
#pragma unroll
  for (int c = 0; c < 2; ++c) {
    kreg[c] = *(const int4*)(kp + kr * 64 + (kc0 + 4 * c) * 8);
    vreg[c] = *(const int4*)(vp + vr * 64 + (vc0 + c) * 8);
  }

  for (int kt = 0; kt < SKV / 64; ++kt) {
    ushort* Kd = (kt & 1) ? Kb1 : Kb0;
    ushort* Vd = (kt & 1) ? Vb1 : Vb0;
#pragma unroll
    for (int c = 0; c < 2; ++c) {
      const int ch = kc0 + 4 * c;
      *(int4*)(Kd + kr * 64 + ((ch ^ (kr & 7)) * 8)) = kreg[c];
      const int vch = vc0 + c;
      const ushort* src = (const ushort*)&vreg[c];
#pragma unroll
      for (int e = 0; e < 8; ++e) {
        const int d = vch * 8 + e;
        Vd[d * 64 + (vr ^ (8 * (d & 7)))] = src[e];
      }
    }
    if (kt < SKV / 64 - 1) {
      const ushort* kp2 = kp + (size_t)(kt + 1) * 64 * 64;
      const ushort* vp2 = vp + (size_t)(kt + 1) * 64 * 64;
#pragma unroll
      for (int c = 0; c < 2; ++c) {
        kreg[c] = *(const int4*)(kp2 + kr * 64 + (kc0 + 4 * c) * 8);
        vreg[c] = *(const int4*)(vp2 + vr * 64 + (vc0 + c) * 8);
      }
    }
    __syncthreads();

    f32x4 sacc[4];
#pragma unroll
    for (int fn = 0; fn < 4; ++fn) sacc[fn] = (f32x4)(0.0f);
#pragma unroll
    for (int ks = 0; ks < 2; ++ks) {
#pragma unroll
      for (int fn = 0; fn < 4; ++fn) {
        const bf16x8 kf = *(const bf16x8*)(
            Kd + (16 * fn + (l & 15)) * 64 + ((8 * (l >> 4) + 32 * ks) ^ (8 * (l & 7))));
        sacc[fn] = __builtin_amdgcn_mfma_f32_16x16x32_bf16(qf[ks], kf, sacc[fn], 0, 0, 0);
      }
    }

    float pvv[4][4];
    float cf[4];
#pragma unroll
    for (int r = 0; r < 4; ++r) {
      float tmax = fmaxf(fmaxf(sacc[0][r], sacc[1][r]), fmaxf(sacc[2][r], sacc[3][r]));
      tmax = fmaxf(tmax, __shfl_xor(tmax, 1));
      tmax = fmaxf(tmax, __shfl_xor(tmax, 2));
      tmax = fmaxf(tmax, __shfl_xor(tmax, 4));
      tmax = fmaxf(tmax, __shfl_xor(tmax, 8));
      const float mn = fmaxf(mrow[r], tmax);
      cf[r] = __expf(mrow[r] - mn);
      mrow[r] = mn;
      float ts = 0.0f;
#pragma unroll
      for (int fn = 0; fn < 4; ++fn) {
        const float e = __expf(sacc[fn][r] - mn);
        pvv[fn][r] = e;
        ts += e;
      }
      ts += __shfl_xor(ts, 1);
      ts += __shfl_xor(ts, 2);
      ts += __shfl_xor(ts, 4);
      ts += __shfl_xor(ts, 8);
      lrow[r] = lrow[r] * cf[r] + ts;
    }
#pragma unroll
    for (int fd = 0; fd < 4; ++fd)
#pragma unroll
      for (int r = 0; r < 4; ++r) accO[fd][r] *= cf[r];

    const int rbase = 4 * (l >> 4);
#pragma unroll
    for (int fn = 0; fn < 4; ++fn)
#pragma unroll
      for (int r = 0; r < 4; ++r) {
        const int row = rbase + r;
        Pw[row * 64 + ((16 * fn + (l & 15)) ^ (8 * (row & 7)))] = f2bf(pvv[fn][r]);
      }

#pragma unroll
    for (int ks = 0; ks < 2; ++ks) {
      const bf16x8 pa = *(const bf16x8*)(
          Pw + (l & 15) * 64 + ((8 * (l >> 4) + 32 * ks) ^ (8 * (l & 7))));
#pragma unroll
      for (int fd = 0; fd < 4; ++fd) {
        const bf16x8 vf = *(const bf16x8*)(
            Vd + (16 * fd + (l & 15)) * 64 + ((8 * (l >> 4) + 32 * ks) ^ (8 * (l & 7))));
        accO[fd] = __builtin_amdgcn_mfma_f32_16x16x32_bf16(pa, vf, accO[fd], 0, 0, 0);
      }
    }
  }

  const int b = bh >> 4, h = bh & 15;
#pragma unroll
  for (int fd = 0; fd < 4; ++fd)
#pragma unroll
    for (int r = 0; r < 4; ++r) {
      const int m = qt * 64 + wid * 16 + 4 * (l >> 4) + r;
      const float val = accO[fd][r] / lrow[r];
      ao[((size_t)b * MLAT + m) * DIMW + h * HDIM + 16 * fd + (l & 15)] = f2bf(val);
    }
}

// ---------------------------------------------------------------------------
extern "C" void kernel_launch(void* const* d_in, const int* in_sizes, int n_in,
                              void* d_out, int out_size, void* d_ws, size_t ws_size,
                              hipStream_t stream) {
  const float* x    = (const float*)d_in[0];
  const float* lat  = (const float*)d_in[1];
  const float* cosT = (const float*)d_in[2];
  const float* sinT = (const float*)d_in[3];
  const float* Wq   = (const float*)d_in[4];
  const float* Wkv  = (const float*)d_in[5];
  const float* Wout = (const float*)d_in[6];
  const float* gx   = (const float*)d_in[7];
  const float* bx   = (const float*)d_in[8];
  const float* gl   = (const float*)d_in[9];
  const float* bl   = (const float*)d_in[10];
  float* out = (float*)d_out;

  ushort* xnb   = (ushort*)d_ws;                        // 8192*1024
  ushort* lnb   = xnb   + (size_t)8192 * 1024;          // 1024*1024
  ushort* WqT   = lnb   + (size_t)1024 * 1024;          // 1024*1024
  ushort* WkvT  = WqT   + (size_t)1024 * 1024;          // 2048*1024
  ushort* WoutT = WkvT  + (size_t)2048 * 1024;          // 1024*1024
  ushort* qwb   = WoutT + (size_t)1024 * 1024;          // 2*16*512*64
  ushort* kwb   = qwb   + (size_t)NB * NH * MLAT * HDIM;// 2*16*4608*64
  ushort* vwb   = kwb   + (size_t)NB * NH * SKV * HDIM;
  ushort* aob   = vwb   + (size_t)NB * NH * SKV * HDIM; // 1024*1024

  ln_kernel<<<dim3(NB * NSEQ), dim3(256), 0, stream>>>(x, gx, bx, xnb);
  ln_kernel<<<dim3(NB * MLAT), dim3(256), 0, stream>>>(lat, gl, bl, lnb);

  tcast_kernel<<<dim3(16, 16), dim3(256), 0, stream>>>(Wq,   WqT,   DIMW, 1024);
  tcast_kernel<<<dim3(32, 16), dim3(256), 0, stream>>>(Wkv,  WkvT,  DIMW, 2048);
  tcast_kernel<<<dim3(16, 16), dim3(256), 0, stream>>>(Wout, WoutT, DIMW, 1024);

  // fused: [q | k_l | v_l] = ln @ [Wq | Wkv]   (M=1024, N=3072)
  gemm_bf16<1><<<dim3(8, 24), dim3(256), 0, stream>>>(
      lnb, WqT, WkvT, qwb, kwb, vwb, nullptr, nullptr);
  // kv_x = xn @ Wkv (M=8192, N=2048), RoPE on k
  gemm_bf16<2><<<dim3(64, 16), dim3(256), 0, stream>>>(
      xnb, WkvT, nullptr, nullptr, kwb, vwb, cosT, sinT);

  attn_mfma<<<dim3(8, 32), dim3(256), 0, stream>>>(qwb, kwb, vwb, aob);

  // out = ao @ Wout (M=1024, N=1024)
  gemm_bf16<0><<<dim3(8, 8), dim3(256), 0, stream>>>(
      aob, WoutT, nullptr, out, nullptr, nullptr, nullptr, nullptr);
}

// Round 15
// 303.165 us; speedup vs baseline: 4.0265x; 1.0951x over previous
//
#include <hip/hip_runtime.h>
#include <hip/hip_bf16.h>

#define DIMW 1024
#define NB 2
#define NSEQ 4096
#define MLAT 512
#define NH 16
#define HDIM 64
#define SKV 4608   // NSEQ + MLAT
#define LNEPS 1e-5f
#define NSPLIT 4
#define TILES_PER_SPLIT (SKV / 64 / NSPLIT)   // 18

typedef __attribute__((ext_vector_type(8))) short bf16x8;
typedef __attribute__((ext_vector_type(4))) float f32x4;

static __device__ __forceinline__ ushort f2bf(float f) {
  __hip_bfloat16 h = __float2bfloat16(f);
  return *reinterpret_cast<ushort*>(&h);
}

// async global->LDS, 16B per lane; LDS dest must be wave-uniform base + lane*16
#define GLOAD_LDS16(gp, lp)                                                    \
  __builtin_amdgcn_global_load_lds(                                            \
      (const __attribute__((address_space(1))) void*)(gp),                     \
      (__attribute__((address_space(3))) void*)(lp), 16, 0, 0)

// ---------------------------------------------------------------------------
// LayerNorm: one block per row of 1024 floats -> bf16 out.
// ---------------------------------------------------------------------------
__global__ __launch_bounds__(256) void ln_kernel(const float* __restrict__ in,
                                                 const float* __restrict__ g,
                                                 const float* __restrict__ bb,
                                                 ushort* __restrict__ out) {
  const int row = blockIdx.x;
  const int tid = threadIdx.x;
  const float4 x = reinterpret_cast<const float4*>(in + (size_t)row * DIMW)[tid];
  float s  = x.x + x.y + x.z + x.w;
  float ss = x.x * x.x + x.y * x.y + x.z * x.z + x.w * x.w;
#pragma unroll
  for (int off = 1; off < 64; off <<= 1) {
    s  += __shfl_xor(s, off);
    ss += __shfl_xor(ss, off);
  }
  __shared__ float red[8];
  const int wid = tid >> 6;
  if ((tid & 63) == 0) { red[wid] = s; red[4 + wid] = ss; }
  __syncthreads();
  const float S  = red[0] + red[1] + red[2] + red[3];
  const float SS = red[4] + red[5] + red[6] + red[7];
  const float mu  = S * (1.0f / DIMW);
  const float var = SS * (1.0f / DIMW) - mu * mu;
  const float rv  = rsqrtf(var + LNEPS);
  const float4 g4 = reinterpret_cast<const float4*>(g)[tid];
  const float4 b4 = reinterpret_cast<const float4*>(bb)[tid];
  ushort4 o = make_ushort4(f2bf((x.x - mu) * rv * g4.x + b4.x),
                           f2bf((x.y - mu) * rv * g4.y + b4.y),
                           f2bf((x.z - mu) * rv * g4.z + b4.z),
                           f2bf((x.w - mu) * rv * g4.w + b4.w));
  *reinterpret_cast<ushort4*>(out + (size_t)row * DIMW + tid * 4) = o;
}

// ---------------------------------------------------------------------------
// Transpose + cast: W [K][Nn] f32 -> WT [Nn][K] bf16. 64x64 tiles.
// ---------------------------------------------------------------------------
__global__ __launch_bounds__(256) void tcast_kernel(const float* __restrict__ W,
                                                    ushort* __restrict__ WT,
                                                    int K, int Nn) {
  __shared__ __align__(16) ushort T[64][72];
  const int t = threadIdx.x;
  const int n0 = blockIdx.x * 64, k0 = blockIdx.y * 64;
#pragma unroll
  for (int i = 0; i < 4; ++i) {
    const int kk = (t >> 4) + 16 * i;
    const int nn = (t & 15) * 4;
    const float4 w = *(const float4*)&W[(size_t)(k0 + kk) * Nn + n0 + nn];
    T[nn + 0][kk] = f2bf(w.x);
    T[nn + 1][kk] = f2bf(w.y);
    T[nn + 2][kk] = f2bf(w.z);
    T[nn + 3][kk] = f2bf(w.w);
  }
  __syncthreads();
#pragma unroll
  for (int i = 0; i < 4; ++i) {
    const int nn = (t >> 4) + 16 * i;
    const int kk = (t & 15) * 4;
    *(ushort4*)&WT[(size_t)(n0 + nn) * K + k0 + kk] = *(ushort4*)&T[nn][kk];
  }
}

// ---------------------------------------------------------------------------
// bf16 MFMA GEMM, m97 staging (verified R14): linear LDS [128][64],
// global_load_lds w=16, 2 barriers per K-step. 128x128 tile, BK=64, 4 waves.
// ---------------------------------------------------------------------------
template <int MODE>
__global__ __launch_bounds__(256, 2) void gemm_bf16(
    const ushort* __restrict__ A, const ushort* __restrict__ B0,
    const ushort* __restrict__ B1,
    void* __restrict__ o0, ushort* __restrict__ o1, ushort* __restrict__ o2,
    const float* __restrict__ cosT, const float* __restrict__ sinT) {
  __shared__ __align__(16) ushort sm[17408];  // 34816 B
  ushort* As = sm;
  ushort* Bs = sm + 8192;

  const int t = threadIdx.x;
  const int lane = t & 63;
  const int wid = t >> 6;
  const int wr = wid >> 1, wc = wid & 1;
  const int arow0 = blockIdx.x * 128;
  const int bcol0 = blockIdx.y * 128;

  const ushort* Bg;
  if (MODE == 1)
    Bg = (bcol0 < 1024) ? (B0 + (size_t)bcol0 * DIMW)
                        : (B1 + (size_t)(bcol0 - 1024) * DIMW);
  else
    Bg = B0 + (size_t)bcol0 * DIMW;
  const ushort* Ag = A + (size_t)arow0 * DIMW;

  const int srow_base = wid * 8;
  const int scol = (lane & 7) * 8;

  f32x4 acc[4][4];
#pragma unroll
  for (int fm = 0; fm < 4; ++fm)
#pragma unroll
    for (int fn = 0; fn < 4; ++fn) acc[fm][fn] = (f32x4)(0.0f);

  const int aoff = (wr * 64 + (lane & 15)) * 64 + (lane >> 4) * 8;
  const int boff = 8192 + (wc * 64 + (lane & 15)) * 64 + (lane >> 4) * 8;

  for (int kt = 0; kt < 16; ++kt) {
    __syncthreads();
#pragma unroll
    for (int r = 0; r < 4; ++r) {
      const int off  = r * 2048 + wid * 512 + lane * 8;
      const int row  = r * 32 + srow_base + (lane >> 3);
      const size_t gofs = (size_t)row * DIMW + kt * 64 + scol;
      GLOAD_LDS16(Ag + gofs, As + off);
      GLOAD_LDS16(Bg + gofs, Bs + off);
    }
    __syncthreads();
#pragma unroll
    for (int s = 0; s < 2; ++s) {
      bf16x8 af[4], bfr[4];
#pragma unroll
      for (int f = 0; f < 4; ++f) {
        af[f]  = *(const bf16x8*)(sm + aoff + f * 16 * 64 + s * 32);
        bfr[f] = *(const bf16x8*)(sm + boff + f * 16 * 64 + s * 32);
      }
#pragma unroll
      for (int fm = 0; fm < 4; ++fm)
#pragma unroll
        for (int fn = 0; fn < 4; ++fn)
          acc[fm][fn] = __builtin_amdgcn_mfma_f32_16x16x32_bf16(
              af[fm], bfr[fn], acc[fm][fn], 0, 0, 0);
    }
  }

  const int lr0 = (lane >> 4) * 4;
  const int lc  = lane & 15;

  if (MODE == 0) {
#pragma unroll
    for (int fm = 0; fm < 4; ++fm)
#pragma unroll
      for (int fn = 0; fn < 4; ++fn)
#pragma unroll
        for (int r = 0; r < 4; ++r) {
          const int row = arow0 + wr * 64 + fm * 16 + lr0 + r;
          const int col = bcol0 + wc * 64 + fn * 16 + lc;
          ((float*)o0)[(size_t)row * DIMW + col] = acc[fm][fn][r];
        }
  } else {
    __syncthreads();
    ushort* Es = sm;
#pragma unroll
    for (int fm = 0; fm < 4; ++fm)
#pragma unroll
      for (int fn = 0; fn < 4; ++fn)
#pragma unroll
        for (int r = 0; r < 4; ++r) {
          const int rl = wr * 64 + fm * 16 + lr0 + r;
          const int cl = wc * 64 + fn * 16 + lc;
          const int row = arow0 + rl;
          const int col = bcol0 + cl;
          float v = acc[fm][fn][r];
          const float p = __shfl_xor(v, 1);
          if (MODE == 1) {
            if (col < 1024) v *= 0.125f;
          } else {
            if (col < 1024) {
              const int hd = col & 63;
              if (hd < 32) {
                const int pos = row & 4095;
                const float cs = cosT[pos * 16 + (hd >> 1)];
                const float sn = sinT[pos * 16 + (hd >> 1)];
                v = (hd & 1) ? fmaf(v, cs, p * sn) : fmaf(v, cs, -p * sn);
              }
            }
          }
          Es[rl * 136 + cl] = f2bf(v);
        }
    __syncthreads();
#pragma unroll
    for (int p8 = 0; p8 < 8; ++p8) {
      const int idx = p8 * 256 + t;
      const int rl  = idx >> 4;
      const int c8  = idx & 15;
      const int row = arow0 + rl;
      const int col0 = bcol0 + c8 * 8;
      const int4 val = *(const int4*)(Es + rl * 136 + c8 * 8);
      ushort* dst;
      if (MODE == 1) {
        const int b = row >> 9, m = row & 511;
        if (col0 < 1024) {
          dst = (ushort*)o0 +
                (size_t)((b * NH + (col0 >> 6)) * MLAT + m) * HDIM + (col0 & 63);
        } else if (col0 < 2048) {
          const int c2 = col0 - 1024;
          dst = o1 + (size_t)((b * NH + (c2 >> 6)) * SKV + NSEQ + m) * HDIM + (c2 & 63);
        } else {
          const int c2 = col0 - 2048;
          dst = o2 + (size_t)((b * NH + (c2 >> 6)) * SKV + NSEQ + m) * HDIM + (c2 & 63);
        }
      } else {
        const int b = row >> 12, pos = row & 4095;
        if (col0 < 1024) {
          dst = o1 + (size_t)((b * NH + (col0 >> 6)) * SKV + pos) * HDIM + (col0 & 63);
        } else {
          const int c2 = col0 - 1024;
          dst = o2 + (size_t)((b * NH + (c2 >> 6)) * SKV + pos) * HDIM + (c2 & 63);
        }
      }
      *(int4*)dst = val;
    }
  }
}

// ---------------------------------------------------------------------------
// bf16 MFMA flash attention, KV-split (NSPLIT=4). Body identical to the
// verified R14 attn_mfma except: each block handles 18 KV tiles and writes
// UNNORMALIZED partial O (f32) + per-row (m,l) to workspace.
// ---------------------------------------------------------------------------
__global__ __launch_bounds__(256) void attn_split(const ushort* __restrict__ q,
                                                  const ushort* __restrict__ k,
                                                  const ushort* __restrict__ v,
                                                  float* __restrict__ Opart,
                                                  float* __restrict__ Ml) {
  __shared__ __align__(16) ushort sm[20480];  // 40 KB
  const int t = threadIdx.x;
  const int l = t & 63;
  const int wid = t >> 6;
  const int qt = blockIdx.x, bh = blockIdx.y, sp = blockIdx.z;
  const size_t kvb = (size_t)bh * SKV * HDIM + (size_t)sp * TILES_PER_SPLIT * 64 * HDIM;

  bf16x8 qf[2];
  {
    const ushort* qa = q + ((size_t)bh * MLAT + qt * 64 + wid * 16 + (l & 15)) * HDIM
                         + 8 * (l >> 4);
    qf[0] = *(const bf16x8*)(qa);
    qf[1] = *(const bf16x8*)(qa + 32);
  }

  ushort* Kb0 = sm;
  ushort* Kb1 = sm + 4096;
  ushort* Vb0 = sm + 8192;
  ushort* Vb1 = sm + 12288;
  ushort* Pw  = sm + 16384 + wid * 1024;

  const int kr  = t >> 2;
  const int kc0 = t & 3;
  const int vr  = t & 63;
  const int vc0 = (t >> 6) * 2;

  f32x4 accO[4];
#pragma unroll
  for (int fd = 0; fd < 4; ++fd) accO[fd] = (f32x4)(0.0f);
  float mrow[4] = {-1e30f, -1e30f, -1e30f, -1e30f};
  float lrow[4] = {0.0f, 0.0f, 0.0f, 0.0f};

  const ushort* kp = k + kvb;
  const ushort* vp = v + kvb;
  int4 kreg[2], vreg[2];
#pragma unroll
  for (int c = 0; c < 2; ++c) {
    kreg[c] = *(const int4*)(kp + kr * 64 + (kc0 + 4 * c) * 8);
    vreg[c] = *(const int4*)(vp + vr * 64 + (vc0 + c) * 8);
  }

  for (int kt = 0; kt < TILES_PER_SPLIT; ++kt) {
    ushort* Kd = (kt & 1) ? Kb1 : Kb0;
    ushort* Vd = (kt & 1) ? Vb1 : Vb0;
#pragma unroll
    for (int c = 0; c < 2; ++c) {
      const int ch = kc0 + 4 * c;
      *(int4*)(Kd + kr * 64 + ((ch ^ (kr & 7)) * 8)) = kreg[c];
      const int vch = vc0 + c;
      const ushort* src = (const ushort*)&vreg[c];
#pragma unroll
      for (int e = 0; e < 8; ++e) {
        const int d = vch * 8 + e;
        Vd[d * 64 + (vr ^ (8 * (d & 7)))] = src[e];
      }
    }
    if (kt < TILES_PER_SPLIT - 1) {
      const ushort* kp2 = kp + (size_t)(kt + 1) * 64 * 64;
      const ushort* vp2 = vp + (size_t)(kt + 1) * 64 * 64;
#pragma unroll
      for (int c = 0; c < 2; ++c) {
        kreg[c] = *(const int4*)(kp2 + kr * 64 + (kc0 + 4 * c) * 8);
        vreg[c] = *(const int4*)(vp2 + vr * 64 + (vc0 + c) * 8);
      }
    }
    __syncthreads();

    f32x4 sacc[4];
#pragma unroll
    for (int fn = 0; fn < 4; ++fn) sacc[fn] = (f32x4)(0.0f);
#pragma unroll
    for (int ks = 0; ks < 2; ++ks) {
#pragma unroll
      for (int fn = 0; fn < 4; ++fn) {
        const bf16x8 kf = *(const bf16x8*)(
            Kd + (16 * fn + (l & 15)) * 64 + ((8 * (l >> 4) + 32 * ks) ^ (8 * (l & 7))));
        sacc[fn] = __builtin_amdgcn_mfma_f32_16x16x32_bf16(qf[ks], kf, sacc[fn], 0, 0, 0);
      }
    }

    float pvv[4][4];
    float cf[4];
#pragma unroll
    for (int r = 0; r < 4; ++r) {
      float tmax = fmaxf(fmaxf(sacc[0][r], sacc[1][r]), fmaxf(sacc[2][r], sacc[3][r]));
      tmax = fmaxf(tmax, __shfl_xor(tmax, 1));
      tmax = fmaxf(tmax, __shfl_xor(tmax, 2));
      tmax = fmaxf(tmax, __shfl_xor(tmax, 4));
      tmax = fmaxf(tmax, __shfl_xor(tmax, 8));
      const float mn = fmaxf(mrow[r], tmax);
      cf[r] = __expf(mrow[r] - mn);
      mrow[r] = mn;
      float ts = 0.0f;
#pragma unroll
      for (int fn = 0; fn < 4; ++fn) {
        const float e = __expf(sacc[fn][r] - mn);
        pvv[fn][r] = e;
        ts += e;
      }
      ts += __shfl_xor(ts, 1);
      ts += __shfl_xor(ts, 2);
      ts += __shfl_xor(ts, 4);
      ts += __shfl_xor(ts, 8);
      lrow[r] = lrow[r] * cf[r] + ts;
    }
#pragma unroll
    for (int fd = 0; fd < 4; ++fd)
#pragma unroll
      for (int r = 0; r < 4; ++r) accO[fd][r] *= cf[r];

    const int rbase = 4 * (l >> 4);
#pragma unroll
    for (int fn = 0; fn < 4; ++fn)
#pragma unroll
      for (int r = 0; r < 4; ++r) {
        const int row = rbase + r;
        Pw[row * 64 + ((16 * fn + (l & 15)) ^ (8 * (row & 7)))] = f2bf(pvv[fn][r]);
      }

#pragma unroll
    for (int ks = 0; ks < 2; ++ks) {
      const bf16x8 pa = *(const bf16x8*)(
          Pw + (l & 15) * 64 + ((8 * (l >> 4) + 32 * ks) ^ (8 * (l & 7))));
#pragma unroll
      for (int fd = 0; fd < 4; ++fd) {
        const bf16x8 vf = *(const bf16x8*)(
            Vd + (16 * fd + (l & 15)) * 64 + ((8 * (l >> 4) + 32 * ks) ^ (8 * (l & 7))));
        accO[fd] = __builtin_amdgcn_mfma_f32_16x16x32_bf16(pa, vf, accO[fd], 0, 0, 0);
      }
    }
  }

  // ---- epilogue: write UNNORMALIZED partial O (f32) + (m,l) per row ----
  const int base = (sp * 32 + bh) * 8 + qt;           // 0..1023
  float* Ob = Opart + (size_t)base * 4096;
#pragma unroll
  for (int fd = 0; fd < 4; ++fd)
#pragma unroll
    for (int r = 0; r < 4; ++r) {
      const int row = wid * 16 + 4 * (l >> 4) + r;    // 0..63
      Ob[row * 64 + 16 * fd + (l & 15)] = accO[fd][r];
    }
  if ((l & 15) == 0) {
#pragma unroll
    for (int r = 0; r < 4; ++r) {
      const int row = wid * 16 + 4 * (l >> 4) + r;
      Ml[(size_t)base * 128 + row * 2]     = mrow[r];
      Ml[(size_t)base * 128 + row * 2 + 1] = lrow[r];
    }
  }
}

// ---------------------------------------------------------------------------
// Combine: one block per (qt, bh); merge NSPLIT partials -> bf16 ao.
// Thread t: row = t>>2 (0..63), dims c0 = (t&3)*16 .. +15.
// ---------------------------------------------------------------------------
__global__ __launch_bounds__(256) void attn_combine(const float* __restrict__ Opart,
                                                    const float* __restrict__ Ml,
                                                    ushort* __restrict__ ao) {
  const int qt = blockIdx.x, bh = blockIdx.y;
  const int t = threadIdx.x;
  const int row = t >> 2;
  const int c0 = (t & 3) * 16;
  const int b = bh >> 4, h = bh & 15;

  int bases[NSPLIT];
  float m[NSPLIT], lv[NSPLIT];
#pragma unroll
  for (int s = 0; s < NSPLIT; ++s) {
    bases[s] = (s * 32 + bh) * 8 + qt;
    m[s]  = Ml[(size_t)bases[s] * 128 + row * 2];
    lv[s] = Ml[(size_t)bases[s] * 128 + row * 2 + 1];
  }
  float mg = fmaxf(fmaxf(m[0], m[1]), fmaxf(m[2], m[3]));
  float w[NSPLIT];
  float lg = 0.0f;
#pragma unroll
  for (int s = 0; s < NSPLIT; ++s) {
    w[s] = __expf(m[s] - mg);
    lg += lv[s] * w[s];
  }
  const float inv = 1.0f / lg;

  float acc[16];
#pragma unroll
  for (int j = 0; j < 16; ++j) acc[j] = 0.0f;
#pragma unroll
  for (int s = 0; s < NSPLIT; ++s) {
    const float* Ob = Opart + (size_t)bases[s] * 4096 + row * 64 + c0;
#pragma unroll
    for (int j4 = 0; j4 < 4; ++j4) {
      const float4 v = *(const float4*)(Ob + j4 * 4);
      acc[j4 * 4 + 0] = fmaf(w[s], v.x, acc[j4 * 4 + 0]);
      acc[j4 * 4 + 1] = fmaf(w[s], v.y, acc[j4 * 4 + 1]);
      acc[j4 * 4 + 2] = fmaf(w[s], v.z, acc[j4 * 4 + 2]);
      acc[j4 * 4 + 3] = fmaf(w[s], v.w, acc[j4 * 4 + 3]);
    }
  }
  ushort* dst = ao + ((size_t)(b * MLAT + qt * 64 + row)) * DIMW + h * HDIM + c0;
#pragma unroll
  for (int j4 = 0; j4 < 4; ++j4) {
    *(ushort4*)(dst + j4 * 4) =
        make_ushort4(f2bf(acc[j4 * 4 + 0] * inv), f2bf(acc[j4 * 4 + 1] * inv),
                     f2bf(acc[j4 * 4 + 2] * inv), f2bf(acc[j4 * 4 + 3] * inv));
  }
}

// ---------------------------------------------------------------------------
extern "C" void kernel_launch(void* const* d_in, const int* in_sizes, int n_in,
                              void* d_out, int out_size, void* d_ws, size_t ws_size,
                              hipStream_t stream) {
  const float* x    = (const float*)d_in[0];
  const float* lat  = (const float*)d_in[1];
  const float* cosT = (const float*)d_in[2];
  const float* sinT = (const float*)d_in[3];
  const float* Wq   = (const float*)d_in[4];
  const float* Wkv  = (const float*)d_in[5];
  const float* Wout = (const float*)d_in[6];
  const float* gx   = (const float*)d_in[7];
  const float* bx   = (const float*)d_in[8];
  const float* gl   = (const float*)d_in[9];
  const float* bl   = (const float*)d_in[10];
  float* out = (float*)d_out;

  ushort* xnb   = (ushort*)d_ws;                        // 8192*1024
  ushort* lnb   = xnb   + (size_t)8192 * 1024;          // 1024*1024
  ushort* WqT   = lnb   + (size_t)1024 * 1024;          // 1024*1024
  ushort* WkvT  = WqT   + (size_t)1024 * 1024;          // 2048*1024
  ushort* WoutT = WkvT  + (size_t)2048 * 1024;          // 1024*1024
  ushort* qwb   = WoutT + (size_t)1024 * 1024;          // 2*16*512*64
  ushort* kwb   = qwb   + (size_t)NB * NH * MLAT * HDIM;// 2*16*4608*64
  ushort* vwb   = kwb   + (size_t)NB * NH * SKV * HDIM;
  ushort* aob   = vwb   + (size_t)NB * NH * SKV * HDIM; // 1024*1024
  float*  opart = (float*)(aob + (size_t)1024 * 1024);  // 1024*4096 f32 (16.8MB)
  float*  mlbuf = opart + (size_t)1024 * 4096;          // 1024*128 f32

  ln_kernel<<<dim3(NB * NSEQ), dim3(256), 0, stream>>>(x, gx, bx, xnb);
  ln_kernel<<<dim3(NB * MLAT), dim3(256), 0, stream>>>(lat, gl, bl, lnb);

  tcast_kernel<<<dim3(16, 16), dim3(256), 0, stream>>>(Wq,   WqT,   DIMW, 1024);
  tcast_kernel<<<dim3(32, 16), dim3(256), 0, stream>>>(Wkv,  WkvT,  DIMW, 2048);
  tcast_kernel<<<dim3(16, 16), dim3(256), 0, stream>>>(Wout, WoutT, DIMW, 1024);

  // fused: [q | k_l | v_l] = ln @ [Wq | Wkv]   (M=1024, N=3072)
  gemm_bf16<1><<<dim3(8, 24), dim3(256), 0, stream>>>(
      lnb, WqT, WkvT, qwb, kwb, vwb, nullptr, nullptr);
  // kv_x = xn @ Wkv (M=8192, N=2048), RoPE on k
  gemm_bf16<2><<<dim3(64, 16), dim3(256), 0, stream>>>(
      xnb, WkvT, nullptr, nullptr, kwb, vwb, cosT, sinT);

  attn_split<<<dim3(8, 32, NSPLIT), dim3(256), 0, stream>>>(
      qwb, kwb, vwb, opart, mlbuf);
  attn_combine<<<dim3(8, 32), dim3(256), 0, stream>>>(opart, mlbuf, aob);

  // out = ao @ Wout (M=1024, N=1024)
  gemm_bf16<0><<<dim3(8, 8), dim3(256), 0, stream>>>(
      aob, WoutT, nullptr, out, nullptr, nullptr, nullptr, nullptr);
}